// Round 3
// baseline (2393.101 us; speedup 1.0000x reference)
//
#include <hip/hip_runtime.h>
#include <math.h>

#define Bsz 1024
#define Npt 50
#define Hd 128
#define G4 512
#define Tt 50
#define NEGC 1000000000.0f
#define CTANH 10.0f

#define OFF_R 0
#define OFF_V 1024
#define OFF_LP 2048
#define OFF_A 2562048
#define OFF_C 2613248
#define OFF_P 2715648

// ws float offsets (all tables; no bulk state)
#define WS_TG 0        // 128 float4 {Mg0, Mg1, vg, cg}
#define WS_TP 512      // 128 float4 {Mp0, Mp1, vp, cp}
#define WS_TQ 1024     // 128 float4 {Pg0, Pg1, cg@Wqp+cp, 0}
#define WS_A0 1536     // 512: We0@Wi
#define WS_A1 2048     // 512: We1@Wi
#define WS_A2 2560     // 512: bemb@Wi + bl
#define WS_A3 3072     // 512: dec_init@Wi + bl   (step 0)
#define WS_CT 3584     // 128 float4 {T0, T1, Tc(+b1), W2}

__device__ __forceinline__ float fsig(float x) {
  return __builtin_amdgcn_rcpf(1.0f + __expf(-x));
}

__device__ __forceinline__ float ftanh(float x) {
  float e = __expf(2.0f * x);
  return 1.0f - 2.0f * __builtin_amdgcn_rcpf(e + 1.0f);
}

__device__ __forceinline__ float dpp_sum_bcast(float x) {
  int v;
  v = __builtin_amdgcn_update_dpp(0, __float_as_int(x), 0x111, 0xf, 0xf, true);
  x += __int_as_float(v);
  v = __builtin_amdgcn_update_dpp(0, __float_as_int(x), 0x112, 0xf, 0xf, true);
  x += __int_as_float(v);
  v = __builtin_amdgcn_update_dpp(0, __float_as_int(x), 0x114, 0xf, 0xf, true);
  x += __int_as_float(v);
  v = __builtin_amdgcn_update_dpp(0, __float_as_int(x), 0x118, 0xf, 0xf, true);
  x += __int_as_float(v);
  v = __builtin_amdgcn_update_dpp(0, __float_as_int(x), 0x142, 0xf, 0xf, true);
  x += __int_as_float(v);
  v = __builtin_amdgcn_update_dpp(0, __float_as_int(x), 0x143, 0xf, 0xf, true);
  x += __int_as_float(v);
  return __int_as_float(__builtin_amdgcn_readlane(__float_as_int(x), 63));
}

// wave64 max via DPP; REQUIRES x >= 0
__device__ __forceinline__ float dpp_max_bcast(float x) {
  int v;
  v = __builtin_amdgcn_update_dpp(0, __float_as_int(x), 0x111, 0xf, 0xf, true);
  x = fmaxf(x, __int_as_float(v));
  v = __builtin_amdgcn_update_dpp(0, __float_as_int(x), 0x112, 0xf, 0xf, true);
  x = fmaxf(x, __int_as_float(v));
  v = __builtin_amdgcn_update_dpp(0, __float_as_int(x), 0x114, 0xf, 0xf, true);
  x = fmaxf(x, __int_as_float(v));
  v = __builtin_amdgcn_update_dpp(0, __float_as_int(x), 0x118, 0xf, 0xf, true);
  x = fmaxf(x, __int_as_float(v));
  v = __builtin_amdgcn_update_dpp(0, __float_as_int(x), 0x142, 0xf, 0xf, true);
  x = fmaxf(x, __int_as_float(v));
  v = __builtin_amdgcn_update_dpp(0, __float_as_int(x), 0x143, 0xf, 0xf, true);
  x = fmaxf(x, __int_as_float(v));
  return __int_as_float(__builtin_amdgcn_readlane(__float_as_int(x), 63));
}

__device__ __forceinline__ float xsum(float x) {
  #pragma unroll
  for (int off = 32; off >= 1; off >>= 1) x += __shfl_xor(x, off, 64);
  return x;
}

// One block, 512 threads: all rank-2 tables + collapsed critic tables.
__global__ __launch_bounds__(512) void k_pre(const float* __restrict__ Wemb,
                                             const float* __restrict__ bemb,
                                             const float* __restrict__ dinit,
                                             const float* __restrict__ Wi,
                                             const float* __restrict__ bl,
                                             const float* __restrict__ Wqp,
                                             const float* __restrict__ Wrg,
                                             const float* __restrict__ Wrp,
                                             const float* __restrict__ vg,
                                             const float* __restrict__ vp,
                                             const float* __restrict__ Wrc,
                                             const float* __restrict__ W1,
                                             const float* __restrict__ b1,
                                             const float* __restrict__ W2,
                                             float* __restrict__ ws) {
  __shared__ float mg_s[2][128], mp_s[2][128], cg_s[128], cp_s[128];
  __shared__ float pg_s[2][128], pc_s[128];
  __shared__ float r0_s[128], r1_s[128], rc_s[128];
  int t = threadIdx.x;
  if (t < 256) {
    int j = t >> 7, hh = t & 127;
    float ag = 0.f, ap = 0.f;
    for (int k = 0; k < 128; ++k) {
      float we = Wemb[j * 128 + k];
      ag = fmaf(we, Wrg[k * 128 + hh], ag);
      ap = fmaf(we, Wrp[k * 128 + hh], ap);
    }
    mg_s[j][hh] = ag; mp_s[j][hh] = ap;
  } else if (t < 384) {
    int hh = t & 127;
    float cgv = 0.f, cpv = 0.f;
    for (int k = 0; k < 128; ++k) {
      float be = bemb[k];
      cgv = fmaf(be, Wrg[k * 128 + hh], cgv);
      cpv = fmaf(be, Wrp[k * 128 + hh], cpv);
    }
    cg_s[hh] = cgv; cp_s[hh] = cpv;
  } else {
    int hh = t & 127;
    float a0 = 0.f, a1 = 0.f, ac = 0.f;
    for (int k = 0; k < 128; ++k) {
      float wr = Wrc[k * 128 + hh];
      a0 = fmaf(Wemb[k], wr, a0);
      a1 = fmaf(Wemb[128 + k], wr, a1);
      ac = fmaf(bemb[k], wr, ac);
    }
    r0_s[hh] = a0; r1_s[hh] = a1; rc_s[hh] = ac;
  }
  __syncthreads();
  if (t < 256) {
    int j = t >> 7, hh = t & 127;
    float pg = 0.f;
    for (int k = 0; k < 128; ++k) pg = fmaf(mg_s[j][k], Wqp[k * 128 + hh], pg);
    pg_s[j][hh] = pg;
  } else if (t < 384) {
    int hh = t & 127;
    float pcv = 0.f;
    for (int k = 0; k < 128; ++k) pcv = fmaf(cg_s[k], Wqp[k * 128 + hh], pcv);
    pc_s[hh] = pcv + cp_s[hh];
  } else {
    int hh = t & 127;
    float t0 = 0.f, t1 = 0.f, tc = 0.f;
    for (int k = 0; k < 128; ++k) {
      float w1 = W1[k * 128 + hh];
      t0 = fmaf(r0_s[k], w1, t0);
      t1 = fmaf(r1_s[k], w1, t1);
      tc = fmaf(rc_s[k], w1, tc);
    }
    float4* w4 = (float4*)ws;
    w4[WS_CT / 4 + hh] = make_float4(t0, t1, tc + b1[hh], W2[hh]);
  }
  __syncthreads();
  if (t < 128) {
    float4* w4 = (float4*)ws;
    w4[WS_TG / 4 + t] = make_float4(mg_s[0][t], mg_s[1][t], vg[t], cg_s[t]);
    w4[WS_TP / 4 + t] = make_float4(mp_s[0][t], mp_s[1][t], vp[t], cp_s[t]);
    w4[WS_TQ / 4 + t] = make_float4(pg_s[0][t], pg_s[1][t], pc_s[t], 0.f);
  }
  {
    int j = t;
    float a0 = 0.f, a1 = 0.f, a2 = 0.f, a3 = 0.f;
    for (int k = 0; k < 128; ++k) {
      float wi = Wi[k * G4 + j];
      a0 = fmaf(Wemb[k], wi, a0);
      a1 = fmaf(Wemb[128 + k], wi, a1);
      a2 = fmaf(bemb[k], wi, a2);
      a3 = fmaf(dinit[k], wi, a3);
    }
    ws[WS_A0 + j] = a0;
    ws[WS_A1 + j] = a1;
    ws[WS_A2 + j] = a2 + bl[j];
    ws[WS_A3 + j] = a3 + bl[j];
  }
}

// 512 blocks x 512 threads (8 waves), 2 rows/block, r0's 5-phase schedule
// with bit-identical per-row arithmetic (8x16 k-split for gates, 4x32-h
// chunks for P4/P5/F). LDS 65 KB -> TWO blocks co-resident per CU: two
// independent barrier domains, so when one block drains at s_barrier the
// other keeps issuing (the r0 36% stall). Wh is streamed from L2 each step
// (same addresses, L2-resident per XCD; never HBM); Wqg stays
// register-resident (32 VGPRs). gpart cols per thread are [4c,4c+4) and
// [256+4c,..) so LDS writes stay 16B-stride (2-way, free).
__global__ __launch_bounds__(512, 4) void k_mega(const float* __restrict__ ip,
                                                 const float* __restrict__ Wh,
                                                 const float* __restrict__ Wqg,
                                                 const float* __restrict__ b2,
                                                 const float* __restrict__ ws,
                                                 float* __restrict__ out) {
  __shared__ __align__(16) float gpart[8][2][G4];     // 32 KB
  __shared__ __align__(16) float qpart[8][2][Hd];     // 8 KB
  __shared__ __align__(16) float up_s[4][2][64];      // 2 KB
  __shared__ __align__(16) float up2_s[4][2][64];     // 2 KB
  __shared__ __align__(16) float qc_s[2][Hd];         // 1 KB
  __shared__ __align__(16) float h_s[2][Hd];
  __shared__ __align__(16) float c_s[2][Hd];
  __shared__ __align__(16) float tg_s[G4];            // {2Mg0,2Mg1,-2vg,2cg}
  __shared__ __align__(16) float tp_s[G4];            // {2Mp0,2Mp1,-2vp,0}
  __shared__ __align__(16) float tq_s[G4];            // {2Pg0,2Pg1,2pc,0}
  __shared__ __align__(16) float ct_s[G4];
  __shared__ __align__(16) float a0_s[G4], a1_s[G4], a2_s[G4], a3_s[G4];
  __shared__ float vsum_s[2][4];                      // sum(v) per 32-h chunk
  __shared__ __align__(16) float ip_s[2][Npt * 2];
  __shared__ float mask_s[2][Npt];
  __shared__ float ch_s[2][Npt * 2];
  __shared__ float sel_s[2][2];

  int t = threadIdx.x, blk = blockIdx.x;
  int w = t >> 6, lane = t & 63;
  int k0 = w * 16;                   // wave w owns k-chunk w (8 chunks x 16)

  // ---- register-resident Wqg slice (32 VGPRs): cols lane*2, lane*2+1 ----
  float wqr[32];
  #pragma unroll
  for (int kk = 0; kk < 16; ++kk)
    *(float2*)&wqr[2 * kk] = *(const float2*)&Wqg[(k0 + kk) * Hd + lane * 2];

  // ---- stage tables (x2 pre-scale) + per-block state ----
  const float4* ws4 = (const float4*)ws;
  if (t < 128) {
    float4 g4 = ws4[WS_TG / 4 + t];
    ((float4*)tg_s)[t] = make_float4(2.f * g4.x, 2.f * g4.y, -2.f * g4.z, 2.f * g4.w);
    float4 p4 = ws4[WS_TP / 4 + t];
    ((float4*)tp_s)[t] = make_float4(2.f * p4.x, 2.f * p4.y, -2.f * p4.z, 0.f);
    float4 q4 = ws4[WS_TQ / 4 + t];
    ((float4*)tq_s)[t] = make_float4(2.f * q4.x, 2.f * q4.y, 2.f * q4.z, 0.f);
    ((float4*)ct_s)[t] = ws4[WS_CT / 4 + t];
  } else if (t < 256) {
    int i = t - 128;
    ((float4*)a0_s)[i] = ((const float4*)(ws + WS_A0))[i];
    ((float4*)a1_s)[i] = ((const float4*)(ws + WS_A1))[i];
    ((float4*)a2_s)[i] = ((const float4*)(ws + WS_A2))[i];
    ((float4*)a3_s)[i] = ((const float4*)(ws + WS_A3))[i];
  }
  if (t < 100) {
    ((float2*)ip_s)[t] = ((const float2*)ip)[blk * 100 + t];
    ((float*)mask_s)[t] = 0.f;
  }
  if (t < 256) {
    int r = t >> 7, hh = t & 127;
    h_s[r][hh] = 0.f;
    c_s[r][hh] = 0.f;
  }
  if (t < 8) {          // vsum per 32-h chunk (raw v from ws tables)
    int which = t >> 2, c = t & 3;
    float sv = 0.f;
    for (int hp = 0; hp < 32; ++hp)
      sv += ws[(which ? WS_TP : WS_TG) + (c * 32 + hp) * 4 + 2];
    vsum_s[which][c] = sv;
  }
  if (t < 4) ((float*)sel_s)[t] = 0.f;
  __syncthreads();

  // C/DE/F wave roles: row cr = w&1, hc = w>>1 in [0,4): 32-h chunk.
  int cr = w & 1, hc = w >> 1;
  float2 pn = make_float2(0.f, 0.f);
  if (lane < Npt) pn = ((float2*)ip_s)[cr * Npt + lane];
  int cA = lane * 4, cB = 256 + lane * 4;   // A1 col ownership
  const float4* Wh4 = (const float4*)Wh;

  for (int s = 0; s < Tt; ++s) {
    // ---- P1: A1 (all waves, Wh streamed) + F(s-1) on waves 6-7 ----
    {
      float hv0[16], hv1[16];
      #pragma unroll
      for (int q4i = 0; q4i < 4; ++q4i) {
        *(float4*)&hv0[q4i * 4] = *(const float4*)&h_s[0][k0 + q4i * 4];
        *(float4*)&hv1[q4i * 4] = *(const float4*)&h_s[1][k0 + q4i * 4];
      }
      float4 a00 = make_float4(0.f, 0.f, 0.f, 0.f);
      float4 a01 = make_float4(0.f, 0.f, 0.f, 0.f);
      float4 a10 = make_float4(0.f, 0.f, 0.f, 0.f);
      float4 a11 = make_float4(0.f, 0.f, 0.f, 0.f);
      #pragma unroll
      for (int kk = 0; kk < 16; ++kk) {
        float4 wA = Wh4[((k0 + kk) * G4 + cA) >> 2];
        float4 wB = Wh4[((k0 + kk) * G4 + cB) >> 2];
        float h0 = hv0[kk], h1 = hv1[kk];
        a00.x = fmaf(h0, wA.x, a00.x); a00.y = fmaf(h0, wA.y, a00.y);
        a00.z = fmaf(h0, wA.z, a00.z); a00.w = fmaf(h0, wA.w, a00.w);
        a01.x = fmaf(h0, wB.x, a01.x); a01.y = fmaf(h0, wB.y, a01.y);
        a01.z = fmaf(h0, wB.z, a01.z); a01.w = fmaf(h0, wB.w, a01.w);
        a10.x = fmaf(h1, wA.x, a10.x); a10.y = fmaf(h1, wA.y, a10.y);
        a10.z = fmaf(h1, wA.z, a10.z); a10.w = fmaf(h1, wA.w, a10.w);
        a11.x = fmaf(h1, wB.x, a11.x); a11.y = fmaf(h1, wB.y, a11.y);
        a11.z = fmaf(h1, wB.z, a11.z); a11.w = fmaf(h1, wB.w, a11.w);
      }
      *(float4*)&gpart[w][0][cA] = a00;
      *(float4*)&gpart[w][0][cB] = a01;
      *(float4*)&gpart[w][1][cA] = a10;
      *(float4*)&gpart[w][1][cB] = a11;

      if (w >= 6 && s > 0) {           // F(s-1), one wave per row
        int row = w & 1, stp = s - 1, b = blk * 2 + row;
        float u = up2_s[0][row][lane] + up2_s[1][row][lane]
                + up2_s[2][row][lane] + up2_s[3][row][lane];
        float x = 0.f, e = 0.f;
        if (lane < Npt) {
          x = CTANH * ftanh(u) - NEGC * mask_s[row][lane];
          e = __expf(x);
        }
        float ssum = dpp_sum_bcast(e);
        float ls = __logf(ssum);
        float prob = e * __builtin_amdgcn_rcpf(ssum);
        if (lane < Npt) {
          out[OFF_LP + ((size_t)b * Tt + stp) * Npt + lane] = x - ls;
          out[OFF_P + ((size_t)b * Tt + stp) * Npt + lane] = prob;
        }
        float mx = dpp_max_bcast(prob);
        unsigned long long bal = __ballot((prob == mx) && (lane < Npt));
        int a = __ffsll(bal) - 1;      // first-index tie-break
        float p0a = ip_s[row][2 * a];
        float p1a = ip_s[row][2 * a + 1];
        if (lane == 0) {
          out[OFF_A + (size_t)b * Tt + stp] = (float)a;
          out[OFF_C + ((size_t)b * Tt + stp) * 2 + 0] = p0a;
          out[OFF_C + ((size_t)b * Tt + stp) * 2 + 1] = p1a;
          ((float2*)ch_s)[row * Npt + stp] = make_float2(p0a, p1a);
          mask_s[row][a] = 1.0f;
          sel_s[row][0] = p0a;
          sel_s[row][1] = p1a;
        }
      }
    }
    __syncthreads();
    // ---- P2: A2 combine + rank-2 x-part + LSTM cell (t<256) ----
    if (t < 256) {
      int r = t >> 7, hh = t & 127;
      float p0 = sel_s[r][0], p1 = sel_s[r][1];
      float g[4];
      #pragma unroll
      for (int gi = 0; gi < 4; ++gi) {
        int j = gi * 128 + hh;
        float x = (s == 0) ? a3_s[j]
                           : fmaf(p0, a0_s[j], fmaf(p1, a1_s[j], a2_s[j]));
        #pragma unroll
        for (int k8 = 0; k8 < 8; ++k8) x += gpart[k8][r][j];
        g[gi] = x;
      }
      float c2 = fsig(g[1]) * c_s[r][hh] + fsig(g[0]) * ftanh(g[2]);
      float h2 = fsig(g[3]) * ftanh(c2);
      c_s[r][hh] = c2;
      h_s[r][hh] = h2;
    }
    __syncthreads();
    // ---- P3: B qpart = h2 @ Wqg (k-split 8-way, register weights) ----
    {
      float hv0[16], hv1[16];
      #pragma unroll
      for (int q4i = 0; q4i < 4; ++q4i) {
        *(float4*)&hv0[q4i * 4] = *(const float4*)&h_s[0][k0 + q4i * 4];
        *(float4*)&hv1[q4i * 4] = *(const float4*)&h_s[1][k0 + q4i * 4];
      }
      float q00 = 0.f, q01 = 0.f, q10 = 0.f, q11 = 0.f;
      #pragma unroll
      for (int kk = 0; kk < 16; ++kk) {
        q00 = fmaf(hv0[kk], wqr[2 * kk], q00);
        q01 = fmaf(hv0[kk], wqr[2 * kk + 1], q01);
        q10 = fmaf(hv1[kk], wqr[2 * kk], q10);
        q11 = fmaf(hv1[kk], wqr[2 * kk + 1], q11);
      }
      *(float2*)&qpart[w][0][lane * 2] = make_float2(q00, q01);
      *(float2*)&qpart[w][1][lane * 2] = make_float2(q10, q11);
    }
    __syncthreads();
    // ---- P4: C glimpse scores; wave=(row,32-h chunk), n per lane ----
    {
      if (lane < 32) {                 // in-wave q combine (x2 scaled)
        int h = hc * 32 + lane;
        float qs = ((float4*)tg_s)[h].w
                 + 2.f * (qpart[0][cr][h] + qpart[1][cr][h] + qpart[2][cr][h]
                        + qpart[3][cr][h] + qpart[4][cr][h] + qpart[5][cr][h]
                        + qpart[6][cr][h] + qpart[7][cr][h]);
        qc_s[cr][h] = qs;
      }
      float ac = vsum_s[0][hc];
      #pragma unroll 8
      for (int hp = 0; hp < 32; ++hp) {
        int h = hc * 32 + hp;
        float4 tg4 = ((float4*)tg_s)[h];
        float a = fmaf(pn.x, tg4.x, fmaf(pn.y, tg4.y, qc_s[cr][h]));
        ac = fmaf(tg4.z, __builtin_amdgcn_rcpf(__expf(a) + 1.0f), ac);
      }
      up_s[hc][cr][lane] = ac;
    }
    __syncthreads();
    // ---- P5: DE glimpse softmax (dup per wave) + pointer scores ----
    {
      float u = up_s[0][cr][lane] + up_s[1][cr][lane]
              + up_s[2][cr][lane] + up_s[3][cr][lane];
      float e = 0.f;
      if (lane < Npt) e = __expf(u - NEGC * mask_s[cr][lane]);
      float ssum = dpp_sum_bcast(e);
      float sx = dpp_sum_bcast(e * pn.x);
      float sy = dpp_sum_bcast(e * pn.y);
      float inv = __builtin_amdgcn_rcpf(ssum);
      float s0 = sx * inv;
      float s1 = sy * inv;
      if (lane < 32) {
        int h = hc * 32 + lane;
        float4 tq4 = ((float4*)tq_s)[h];
        qc_s[cr][h] = fmaf(s0, tq4.x, fmaf(s1, tq4.y, tq4.z));
      }
      float ac = vsum_s[1][hc];
      #pragma unroll 8
      for (int hp = 0; hp < 32; ++hp) {
        int h = hc * 32 + hp;
        float4 tp4 = ((float4*)tp_s)[h];
        float a = fmaf(pn.x, tp4.x, fmaf(pn.y, tp4.y, qc_s[cr][h]));
        ac = fmaf(tp4.z, __builtin_amdgcn_rcpf(__expf(a) + 1.0f), ac);
      }
      up2_s[hc][cr][lane] = ac;
    }
    __syncthreads();
  }

  // ---- drain: F(Tt-1) on waves 6-7 ----
  if (w >= 6) {
    int row = w & 1, stp = Tt - 1, b = blk * 2 + row;
    float u = up2_s[0][row][lane] + up2_s[1][row][lane]
            + up2_s[2][row][lane] + up2_s[3][row][lane];
    float x = 0.f, e = 0.f;
    if (lane < Npt) {
      x = CTANH * ftanh(u) - NEGC * mask_s[row][lane];
      e = __expf(x);
    }
    float ssum = dpp_sum_bcast(e);
    float ls = __logf(ssum);
    float prob = e * __builtin_amdgcn_rcpf(ssum);
    if (lane < Npt) {
      out[OFF_LP + ((size_t)b * Tt + stp) * Npt + lane] = x - ls;
      out[OFF_P + ((size_t)b * Tt + stp) * Npt + lane] = prob;
    }
    float mx = dpp_max_bcast(prob);
    unsigned long long bal = __ballot((prob == mx) && (lane < Npt));
    int a = __ffsll(bal) - 1;
    float p0a = ip_s[row][2 * a];
    float p1a = ip_s[row][2 * a + 1];
    if (lane == 0) {
      out[OFF_A + (size_t)b * Tt + stp] = (float)a;
      out[OFF_C + ((size_t)b * Tt + stp) * 2 + 0] = p0a;
      out[OFF_C + ((size_t)b * Tt + stp) * 2 + 1] = p1a;
      ((float2*)ch_s)[row * Npt + stp] = make_float2(p0a, p1a);
      sel_s[row][0] = p0a;
      sel_s[row][1] = p1a;
    }
  }
  __syncthreads();

  // ---- epilogue: collapsed critic + tour length ----
  if (w < 2) {
    int r = w, b = blk * 2 + r;
    float p0 = sel_s[r][0], p1 = sel_s[r][1];
    float4 ct0 = ((float4*)ct_s)[lane];
    float4 ct1 = ((float4*)ct_s)[64 + lane];
    float t1a = fmaxf(fmaf(p0, ct0.x, fmaf(p1, ct0.y, ct0.z)), 0.f);
    float t1b = fmaxf(fmaf(p0, ct1.x, fmaf(p1, ct1.y, ct1.z)), 0.f);
    float sv = xsum(t1a * ct0.w + t1b * ct1.w);
    if (lane == 0) out[OFF_V + b] = sv + b2[0];
    float rr = 0.f;
    if (lane < Npt) {
      float2 c0 = ((float2*)ch_s)[r * Npt + lane];
      float2 c1 = ((float2*)ch_s)[r * Npt + ((lane == Npt - 1) ? 0 : lane + 1)];
      float dx = c1.x - c0.x, dy = c1.y - c0.y;
      rr = sqrtf(dx * dx + dy * dy + 1e-10f);
    }
    rr = xsum(rr);
    if (lane == 0) out[OFF_R + b] = rr;
  }
}

extern "C" void kernel_launch(void* const* d_in, const int* in_sizes, int n_in,
                              void* d_out, int out_size, void* d_ws, size_t ws_size,
                              hipStream_t stream) {
  (void)in_sizes; (void)n_in; (void)out_size; (void)ws_size;
  const float* ip    = (const float*)d_in[0];
  const float* Wemb  = (const float*)d_in[1];
  const float* bemb  = (const float*)d_in[2];
  const float* dinit = (const float*)d_in[3];
  const float* Wi    = (const float*)d_in[4];
  const float* Wh    = (const float*)d_in[5];
  const float* bl    = (const float*)d_in[6];
  const float* Wqg   = (const float*)d_in[7];
  const float* Wrg   = (const float*)d_in[8];
  const float* vg    = (const float*)d_in[9];
  const float* Wqp   = (const float*)d_in[10];
  const float* Wrp   = (const float*)d_in[11];
  const float* vp    = (const float*)d_in[12];
  // d_in[13..16], d_in[18] dead: critic N=1 softmax == 1 => hy = e_c
  const float* Wrc   = (const float*)d_in[17];
  const float* W1    = (const float*)d_in[19];
  const float* b1    = (const float*)d_in[20];
  const float* W2    = (const float*)d_in[21];
  const float* b2    = (const float*)d_in[22];
  float* out = (float*)d_out;
  float* ws  = (float*)d_ws;

  k_pre<<<1, 512, 0, stream>>>(Wemb, bemb, dinit, Wi, bl, Wqp, Wrg, Wrp,
                               vg, vp, Wrc, W1, b1, W2, ws);
  k_mega<<<512, 512, 0, stream>>>(ip, Wh, Wqg, b2, ws, out);
}

// Round 4
// 653.251 us; speedup vs baseline: 3.6634x; 3.6634x over previous
//
#include <hip/hip_runtime.h>
#include <math.h>

#define Bsz 1024
#define Npt 50
#define Hd 128
#define G4 512
#define Tt 50
#define NEGC 1000000000.0f
#define CTANH 10.0f

#define OFF_R 0
#define OFF_V 1024
#define OFF_LP 2048
#define OFF_A 2562048
#define OFF_C 2613248
#define OFF_P 2715648

// ws float offsets (all tables; no bulk state)
#define WS_TG 0        // 128 float4 {Mg0, Mg1, vg, cg}
#define WS_TP 512      // 128 float4 {Mp0, Mp1, vp, cp}
#define WS_TQ 1024     // 128 float4 {Pg0, Pg1, cg@Wqp+cp, 0}
#define WS_A0 1536     // 512: We0@Wi
#define WS_A1 2048     // 512: We1@Wi
#define WS_A2 2560     // 512: bemb@Wi + bl
#define WS_A3 3072     // 512: dec_init@Wi + bl   (step 0)
#define WS_CT 3584     // 128 float4 {T0, T1, Tc(+b1), W2}

__device__ __forceinline__ float fsig(float x) {
  return __builtin_amdgcn_rcpf(1.0f + __expf(-x));
}

__device__ __forceinline__ float ftanh(float x) {
  float e = __expf(2.0f * x);
  return 1.0f - 2.0f * __builtin_amdgcn_rcpf(e + 1.0f);
}

__device__ __forceinline__ float dpp_sum_bcast(float x) {
  int v;
  v = __builtin_amdgcn_update_dpp(0, __float_as_int(x), 0x111, 0xf, 0xf, true);
  x += __int_as_float(v);
  v = __builtin_amdgcn_update_dpp(0, __float_as_int(x), 0x112, 0xf, 0xf, true);
  x += __int_as_float(v);
  v = __builtin_amdgcn_update_dpp(0, __float_as_int(x), 0x114, 0xf, 0xf, true);
  x += __int_as_float(v);
  v = __builtin_amdgcn_update_dpp(0, __float_as_int(x), 0x118, 0xf, 0xf, true);
  x += __int_as_float(v);
  v = __builtin_amdgcn_update_dpp(0, __float_as_int(x), 0x142, 0xf, 0xf, true);
  x += __int_as_float(v);
  v = __builtin_amdgcn_update_dpp(0, __float_as_int(x), 0x143, 0xf, 0xf, true);
  x += __int_as_float(v);
  return __int_as_float(__builtin_amdgcn_readlane(__float_as_int(x), 63));
}

// wave64 max via DPP; REQUIRES x >= 0
__device__ __forceinline__ float dpp_max_bcast(float x) {
  int v;
  v = __builtin_amdgcn_update_dpp(0, __float_as_int(x), 0x111, 0xf, 0xf, true);
  x = fmaxf(x, __int_as_float(v));
  v = __builtin_amdgcn_update_dpp(0, __float_as_int(x), 0x112, 0xf, 0xf, true);
  x = fmaxf(x, __int_as_float(v));
  v = __builtin_amdgcn_update_dpp(0, __float_as_int(x), 0x114, 0xf, 0xf, true);
  x = fmaxf(x, __int_as_float(v));
  v = __builtin_amdgcn_update_dpp(0, __float_as_int(x), 0x118, 0xf, 0xf, true);
  x = fmaxf(x, __int_as_float(v));
  v = __builtin_amdgcn_update_dpp(0, __float_as_int(x), 0x142, 0xf, 0xf, true);
  x = fmaxf(x, __int_as_float(v));
  v = __builtin_amdgcn_update_dpp(0, __float_as_int(x), 0x143, 0xf, 0xf, true);
  x = fmaxf(x, __int_as_float(v));
  return __int_as_float(__builtin_amdgcn_readlane(__float_as_int(x), 63));
}

__device__ __forceinline__ float xsum(float x) {
  #pragma unroll
  for (int off = 32; off >= 1; off >>= 1) x += __shfl_xor(x, off, 64);
  return x;
}

// One block, 512 threads: all rank-2 tables + collapsed critic tables.
__global__ __launch_bounds__(512) void k_pre(const float* __restrict__ Wemb,
                                             const float* __restrict__ bemb,
                                             const float* __restrict__ dinit,
                                             const float* __restrict__ Wi,
                                             const float* __restrict__ bl,
                                             const float* __restrict__ Wqp,
                                             const float* __restrict__ Wrg,
                                             const float* __restrict__ Wrp,
                                             const float* __restrict__ vg,
                                             const float* __restrict__ vp,
                                             const float* __restrict__ Wrc,
                                             const float* __restrict__ W1,
                                             const float* __restrict__ b1,
                                             const float* __restrict__ W2,
                                             float* __restrict__ ws) {
  __shared__ float mg_s[2][128], mp_s[2][128], cg_s[128], cp_s[128];
  __shared__ float pg_s[2][128], pc_s[128];
  __shared__ float r0_s[128], r1_s[128], rc_s[128];
  int t = threadIdx.x;
  if (t < 256) {
    int j = t >> 7, hh = t & 127;
    float ag = 0.f, ap = 0.f;
    for (int k = 0; k < 128; ++k) {
      float we = Wemb[j * 128 + k];
      ag = fmaf(we, Wrg[k * 128 + hh], ag);
      ap = fmaf(we, Wrp[k * 128 + hh], ap);
    }
    mg_s[j][hh] = ag; mp_s[j][hh] = ap;
  } else if (t < 384) {
    int hh = t & 127;
    float cgv = 0.f, cpv = 0.f;
    for (int k = 0; k < 128; ++k) {
      float be = bemb[k];
      cgv = fmaf(be, Wrg[k * 128 + hh], cgv);
      cpv = fmaf(be, Wrp[k * 128 + hh], cpv);
    }
    cg_s[hh] = cgv; cp_s[hh] = cpv;
  } else {
    int hh = t & 127;
    float a0 = 0.f, a1 = 0.f, ac = 0.f;
    for (int k = 0; k < 128; ++k) {
      float wr = Wrc[k * 128 + hh];
      a0 = fmaf(Wemb[k], wr, a0);
      a1 = fmaf(Wemb[128 + k], wr, a1);
      ac = fmaf(bemb[k], wr, ac);
    }
    r0_s[hh] = a0; r1_s[hh] = a1; rc_s[hh] = ac;
  }
  __syncthreads();
  if (t < 256) {
    int j = t >> 7, hh = t & 127;
    float pg = 0.f;
    for (int k = 0; k < 128; ++k) pg = fmaf(mg_s[j][k], Wqp[k * 128 + hh], pg);
    pg_s[j][hh] = pg;
  } else if (t < 384) {
    int hh = t & 127;
    float pcv = 0.f;
    for (int k = 0; k < 128; ++k) pcv = fmaf(cg_s[k], Wqp[k * 128 + hh], pcv);
    pc_s[hh] = pcv + cp_s[hh];
  } else {
    int hh = t & 127;
    float t0 = 0.f, t1 = 0.f, tc = 0.f;
    for (int k = 0; k < 128; ++k) {
      float w1 = W1[k * 128 + hh];
      t0 = fmaf(r0_s[k], w1, t0);
      t1 = fmaf(r1_s[k], w1, t1);
      tc = fmaf(rc_s[k], w1, tc);
    }
    float4* w4 = (float4*)ws;
    w4[WS_CT / 4 + hh] = make_float4(t0, t1, tc + b1[hh], W2[hh]);
  }
  __syncthreads();
  if (t < 128) {
    float4* w4 = (float4*)ws;
    w4[WS_TG / 4 + t] = make_float4(mg_s[0][t], mg_s[1][t], vg[t], cg_s[t]);
    w4[WS_TP / 4 + t] = make_float4(mp_s[0][t], mp_s[1][t], vp[t], cp_s[t]);
    w4[WS_TQ / 4 + t] = make_float4(pg_s[0][t], pg_s[1][t], pc_s[t], 0.f);
  }
  {
    int j = t;
    float a0 = 0.f, a1 = 0.f, a2 = 0.f, a3 = 0.f;
    for (int k = 0; k < 128; ++k) {
      float wi = Wi[k * G4 + j];
      a0 = fmaf(Wemb[k], wi, a0);
      a1 = fmaf(Wemb[128 + k], wi, a1);
      a2 = fmaf(bemb[k], wi, a2);
      a3 = fmaf(dinit[k], wi, a3);
    }
    ws[WS_A0 + j] = a0;
    ws[WS_A1 + j] = a1;
    ws[WS_A2 + j] = a2 + bl[j];
    ws[WS_A3 + j] = a3 + bl[j];
  }
}

// Persistent: 256 blocks x 1024 threads (16 waves), 4 rows/block, Wh/Wqg
// register-resident (r3 proved L2-streaming Wh catastrophically misses).
// Restructured sync, bit-identical math vs the 620us r0 kernel:
//  - 3 global barriers/step (was 5): G1->P2, G2->P3, G3->section.
//  - Section: per row-group (4 waves, cr=w&3) P4 -> lsync -> P5 -> lsync ->
//    F(s) on hc==3, with A1(s+1) split around P4 (group cr does cr rows
//    before P4, rest after F) -> deliberate group stagger so sigmoid-loop
//    trans work co-issues with A1 FMA work across waves. lsync = 4-wave
//    LDS-atomic rendezvous (monotone counter, release add + acquire spin).
//  - A1 legality: reads only h_s (stable in section), writes gpart (read
//    only by P2 after G1). F's global stores drain during A1-post.
//  - A1(0) at h=0 is exactly +0 -> zero-init gpart replaces it.
__global__ __launch_bounds__(1024, 4) void k_mega(const float* __restrict__ ip,
                                                  const float* __restrict__ Wh,
                                                  const float* __restrict__ Wqg,
                                                  const float* __restrict__ b2,
                                                  const float* __restrict__ ws,
                                                  float* __restrict__ out) {
  __shared__ __align__(16) float gpart[8][4][G4];     // 64 KB
  __shared__ __align__(16) float qpart[8][4][Hd];     // 16 KB
  __shared__ __align__(16) float up_s[4][4][64];      // 4 KB glimpse partials
  __shared__ __align__(16) float up2_s[4][4][64];     // 4 KB pointer partials
  __shared__ __align__(16) float qc_s[4][Hd];         // 2 KB query exchange
  __shared__ __align__(16) float h_s[4][Hd];
  __shared__ __align__(16) float c_s[4][Hd];
  __shared__ __align__(16) float tg_s[G4];            // {2Mg0,2Mg1,-2vg,2cg}
  __shared__ __align__(16) float tp_s[G4];            // {2Mp0,2Mp1,-2vp,0}
  __shared__ __align__(16) float tq_s[G4];            // {2Pg0,2Pg1,2pc,0}
  __shared__ __align__(16) float ct_s[G4];
  __shared__ __align__(16) float a0_s[G4], a1_s[G4], a2_s[G4], a3_s[G4];
  __shared__ float vsum_s[2][4];                      // sum(v) per 32-h chunk
  __shared__ __align__(16) float ip_s[4][Npt * 2];
  __shared__ float mask_s[4][Npt];
  __shared__ float ch_s[4][Npt * 2];
  __shared__ float sel_s[4][2];
  __shared__ int ctr_s[4];                            // group rendezvous

  int t = threadIdx.x, blk = blockIdx.x;
  int w = t >> 6, lane = t & 63;
  int kh = t >> 7, jt = t & 127;     // 8 k-chunks x 128 cols
  int k0q = kh * 16;

  // ---- register-resident weights ----
  float4 wv[16];                     // Wh[kh*16 .. +16)[jt*4 .. +4)
  #pragma unroll
  for (int j = 0; j < 16; ++j)
    wv[j] = *(const float4*)&Wh[(kh * 16 + j) * G4 + jt * 4];
  float wqr[16];                     // Wqg[kh*16 .. +16)[jt]
  #pragma unroll
  for (int j = 0; j < 16; ++j)
    wqr[j] = Wqg[(kh * 16 + j) * Hd + jt];

  // ---- stage tables (x2 pre-scale) + per-block state ----
  const float4* ws4 = (const float4*)ws;
  if (t < 128) {
    float4 g4 = ws4[WS_TG / 4 + t];
    ((float4*)tg_s)[t] = make_float4(2.f * g4.x, 2.f * g4.y, -2.f * g4.z, 2.f * g4.w);
    float4 p4 = ws4[WS_TP / 4 + t];
    ((float4*)tp_s)[t] = make_float4(2.f * p4.x, 2.f * p4.y, -2.f * p4.z, 0.f);
    float4 q4 = ws4[WS_TQ / 4 + t];
    ((float4*)tq_s)[t] = make_float4(2.f * q4.x, 2.f * q4.y, 2.f * q4.z, 0.f);
    ((float4*)ct_s)[t] = ws4[WS_CT / 4 + t];
  } else if (t < 256) {
    int i = t - 128;
    ((float4*)a0_s)[i] = ((const float4*)(ws + WS_A0))[i];
    ((float4*)a1_s)[i] = ((const float4*)(ws + WS_A1))[i];
    ((float4*)a2_s)[i] = ((const float4*)(ws + WS_A2))[i];
    ((float4*)a3_s)[i] = ((const float4*)(ws + WS_A3))[i];
  }
  if (t < 200) {
    ((float2*)ip_s)[t] = ((const float2*)ip)[blk * 200 + t];
    ((float*)mask_s)[t] = 0.f;
  }
  if (t < 512) {
    int r = t >> 7, hh = t & 127;
    h_s[r][hh] = 0.f;
    c_s[r][hh] = 0.f;
  }
  if (t < 8) {          // vsum per 32-h chunk (raw v from ws tables)
    int which = t >> 2, c = t & 3;
    float sv = 0.f;
    for (int hp = 0; hp < 32; ++hp)
      sv += ws[(which ? WS_TP : WS_TG) + (c * 32 + hp) * 4 + 2];
    vsum_s[which][c] = sv;
  }
  if (t < 8) ((float*)sel_s)[t] = 0.f;
  if (t < 4) ctr_s[t] = 0;
  {  // zero-init gpart == A1 at h=0 (exact +0), replaces step-0 A1 phase
    float4 z4 = make_float4(0.f, 0.f, 0.f, 0.f);
    #pragma unroll
    for (int i = 0; i < 4; ++i) ((float4*)gpart)[t * 4 + i] = z4;
  }
  __syncthreads();

  // C/DE/F wave roles: row = w&3, hc = w>>2 in [0,4): 32-h chunk.
  int cr = w & 3, hc = w >> 2;
  float2 pn = make_float2(0.f, 0.f);
  if (lane < Npt) pn = ((float2*)ip_s)[cr * Npt + lane];

  int lt = 0;  // rendezvous target (monotone, +4 per lsync)
  auto lsync = [&]() {
    lt += 4;
    if (lane == 0)
      __hip_atomic_fetch_add(&ctr_s[cr], 1, __ATOMIC_RELEASE,
                             __HIP_MEMORY_SCOPE_WORKGROUP);
    while (__hip_atomic_load(&ctr_s[cr], __ATOMIC_ACQUIRE,
                             __HIP_MEMORY_SCOPE_WORKGROUP) < lt)
      __builtin_amdgcn_s_sleep(1);
  };

  auto A1row = [&](int r) {    // one row of gates k-slice (bit-identical r0)
    float hv[16];
    #pragma unroll
    for (int q4i = 0; q4i < 4; ++q4i)
      *(float4*)&hv[q4i * 4] = *(const float4*)&h_s[r][k0q + q4i * 4];
    float a0 = 0.f, a1 = 0.f, a2 = 0.f, a3 = 0.f;
    #pragma unroll
    for (int kk = 0; kk < 16; ++kk) {
      float4 wj = wv[kk];
      a0 = fmaf(hv[kk], wj.x, a0);
      a1 = fmaf(hv[kk], wj.y, a1);
      a2 = fmaf(hv[kk], wj.z, a2);
      a3 = fmaf(hv[kk], wj.w, a3);
    }
    *(float4*)&gpart[kh][r][jt * 4] = make_float4(a0, a1, a2, a3);
  };

  for (int s = 0; s < Tt; ++s) {
    // ---- G1: gates (section A1 of s) + sel (F of s-1) ready ----
    __syncthreads();
    // ---- P2: A2 combine + rank-2 x-part + LSTM cell (t<512) ----
    if (t < 512) {
      int r = t >> 7, hh = t & 127;
      float p0 = sel_s[r][0], p1 = sel_s[r][1];
      float g[4];
      #pragma unroll
      for (int gi = 0; gi < 4; ++gi) {
        int j = gi * 128 + hh;
        float x = (s == 0) ? a3_s[j]
                           : fmaf(p0, a0_s[j], fmaf(p1, a1_s[j], a2_s[j]));
        #pragma unroll
        for (int k8 = 0; k8 < 8; ++k8) x += gpart[k8][r][j];
        g[gi] = x;
      }
      float c2 = fsig(g[1]) * c_s[r][hh] + fsig(g[0]) * ftanh(g[2]);
      float h2 = fsig(g[3]) * ftanh(c2);
      c_s[r][hh] = c2;
      h_s[r][hh] = h2;
    }
    __syncthreads();   // G2: h2 ready for all
    // ---- P3: qpart = h2 @ Wqg (k-split 8-way, register weights) ----
    {
      #pragma unroll
      for (int r = 0; r < 4; ++r) {
        float hv[16];
        #pragma unroll
        for (int q4i = 0; q4i < 4; ++q4i)
          *(float4*)&hv[q4i * 4] = *(const float4*)&h_s[r][k0q + q4i * 4];
        float a = 0.f;
        #pragma unroll
        for (int kk = 0; kk < 16; ++kk) a = fmaf(hv[kk], wqr[kk], a);
        qpart[kh][r][jt] = a;
      }
    }
    __syncthreads();   // G3: qpart ready -> row-group section
    // ---- stagger: group cr runs cr rows of A1(s+1) before P4 ----
    if (s + 1 < Tt) {
      for (int r = 0; r < cr; ++r) A1row(r);
    }
    // ---- P4: C glimpse scores; wave=(row,32-h chunk), n per lane ----
    {
      if (lane < 32) {                 // in-wave q combine (x2 scaled)
        int h = hc * 32 + lane;
        float qs = ((float4*)tg_s)[h].w
                 + 2.f * (qpart[0][cr][h] + qpart[1][cr][h] + qpart[2][cr][h]
                        + qpart[3][cr][h] + qpart[4][cr][h] + qpart[5][cr][h]
                        + qpart[6][cr][h] + qpart[7][cr][h]);
        qc_s[cr][h] = qs;
      }
      float ac = vsum_s[0][hc];
      #pragma unroll 8
      for (int hp = 0; hp < 32; ++hp) {
        int h = hc * 32 + hp;
        float4 tg4 = ((float4*)tg_s)[h];
        float a = fmaf(pn.x, tg4.x, fmaf(pn.y, tg4.y, qc_s[cr][h]));
        ac = fmaf(tg4.z, __builtin_amdgcn_rcpf(__expf(a) + 1.0f), ac);
      }
      up_s[hc][cr][lane] = ac;
    }
    lsync();           // group: up chunks ready
    // ---- P5: DE glimpse softmax (dup per wave) + pointer scores ----
    {
      float u = up_s[0][cr][lane] + up_s[1][cr][lane]
              + up_s[2][cr][lane] + up_s[3][cr][lane];
      float e = 0.f;
      if (lane < Npt) e = __expf(u - NEGC * mask_s[cr][lane]);
      float ssum = dpp_sum_bcast(e);
      float sx = dpp_sum_bcast(e * pn.x);
      float sy = dpp_sum_bcast(e * pn.y);
      float inv = __builtin_amdgcn_rcpf(ssum);
      float s0 = sx * inv;
      float s1 = sy * inv;
      if (lane < 32) {
        int h = hc * 32 + lane;
        float4 tq4 = ((float4*)tq_s)[h];
        qc_s[cr][h] = fmaf(s0, tq4.x, fmaf(s1, tq4.y, tq4.z));
      }
      float ac = vsum_s[1][hc];
      #pragma unroll 8
      for (int hp = 0; hp < 32; ++hp) {
        int h = hc * 32 + hp;
        float4 tp4 = ((float4*)tp_s)[h];
        float a = fmaf(pn.x, tp4.x, fmaf(pn.y, tp4.y, qc_s[cr][h]));
        ac = fmaf(tp4.z, __builtin_amdgcn_rcpf(__expf(a) + 1.0f), ac);
      }
      up2_s[hc][cr][lane] = ac;
    }
    lsync();           // group: up2 chunks ready
    // ---- F(s): pointer softmax + argmax + outputs, one wave per row ----
    if (hc == 3) {
      int row = cr, b = blk * 4 + row;
      float u = up2_s[0][row][lane] + up2_s[1][row][lane]
              + up2_s[2][row][lane] + up2_s[3][row][lane];
      float x = 0.f, e = 0.f;
      if (lane < Npt) {
        x = CTANH * ftanh(u) - NEGC * mask_s[row][lane];
        e = __expf(x);
      }
      float ssum = dpp_sum_bcast(e);
      float ls = __logf(ssum);
      float prob = e * __builtin_amdgcn_rcpf(ssum);
      if (lane < Npt) {
        out[OFF_LP + ((size_t)b * Tt + s) * Npt + lane] = x - ls;
        out[OFF_P + ((size_t)b * Tt + s) * Npt + lane] = prob;
      }
      float mx = dpp_max_bcast(prob);
      unsigned long long bal = __ballot((prob == mx) && (lane < Npt));
      int a = __ffsll(bal) - 1;      // first-index tie-break
      float p0a = ip_s[row][2 * a];
      float p1a = ip_s[row][2 * a + 1];
      if (lane == 0) {
        out[OFF_A + (size_t)b * Tt + s] = (float)a;
        out[OFF_C + ((size_t)b * Tt + s) * 2 + 0] = p0a;
        out[OFF_C + ((size_t)b * Tt + s) * 2 + 1] = p1a;
        ((float2*)ch_s)[row * Npt + s] = make_float2(p0a, p1a);
        mask_s[row][a] = 1.0f;
        sel_s[row][0] = p0a;
        sel_s[row][1] = p1a;
      }
    }
    // ---- A1(s+1) remaining rows (hides F's store drain too) ----
    if (s + 1 < Tt) {
      for (int r = cr; r < 4; ++r) A1row(r);
    }
  }
  __syncthreads();

  // ---- epilogue: collapsed critic + tour length ----
  if (w < 4) {
    int r = w, b = blk * 4 + r;
    float p0 = sel_s[r][0], p1 = sel_s[r][1];
    float4 ct0 = ((float4*)ct_s)[lane];
    float4 ct1 = ((float4*)ct_s)[64 + lane];
    float t1a = fmaxf(fmaf(p0, ct0.x, fmaf(p1, ct0.y, ct0.z)), 0.f);
    float t1b = fmaxf(fmaf(p0, ct1.x, fmaf(p1, ct1.y, ct1.z)), 0.f);
    float sv = xsum(t1a * ct0.w + t1b * ct1.w);
    if (lane == 0) out[OFF_V + b] = sv + b2[0];
    float rr = 0.f;
    if (lane < Npt) {
      float2 c0 = ((float2*)ch_s)[r * Npt + lane];
      float2 c1 = ((float2*)ch_s)[r * Npt + ((lane == Npt - 1) ? 0 : lane + 1)];
      float dx = c1.x - c0.x, dy = c1.y - c0.y;
      rr = sqrtf(dx * dx + dy * dy + 1e-10f);
    }
    rr = xsum(rr);
    if (lane == 0) out[OFF_R + b] = rr;
  }
}

extern "C" void kernel_launch(void* const* d_in, const int* in_sizes, int n_in,
                              void* d_out, int out_size, void* d_ws, size_t ws_size,
                              hipStream_t stream) {
  (void)in_sizes; (void)n_in; (void)out_size; (void)ws_size;
  const float* ip    = (const float*)d_in[0];
  const float* Wemb  = (const float*)d_in[1];
  const float* bemb  = (const float*)d_in[2];
  const float* dinit = (const float*)d_in[3];
  const float* Wi    = (const float*)d_in[4];
  const float* Wh    = (const float*)d_in[5];
  const float* bl    = (const float*)d_in[6];
  const float* Wqg   = (const float*)d_in[7];
  const float* Wrg   = (const float*)d_in[8];
  const float* vg    = (const float*)d_in[9];
  const float* Wqp   = (const float*)d_in[10];
  const float* Wrp   = (const float*)d_in[11];
  const float* vp    = (const float*)d_in[12];
  // d_in[13..16], d_in[18] dead: critic N=1 softmax == 1 => hy = e_c
  const float* Wrc   = (const float*)d_in[17];
  const float* W1    = (const float*)d_in[19];
  const float* b1    = (const float*)d_in[20];
  const float* W2    = (const float*)d_in[21];
  const float* b2    = (const float*)d_in[22];
  float* out = (float*)d_out;
  float* ws  = (float*)d_ws;

  k_pre<<<1, 512, 0, stream>>>(Wemb, bemb, dinit, Wi, bl, Wqp, Wrg, Wrp,
                               vg, vp, Wrc, W1, b1, W2, ws);
  k_mega<<<256, 1024, 0, stream>>>(ip, Wh, Wqg, b2, ws, out);
}

// Round 5
// 623.662 us; speedup vs baseline: 3.8372x; 1.0474x over previous
//
#include <hip/hip_runtime.h>
#include <math.h>

#define Bsz 1024
#define Npt 50
#define Hd 128
#define G4 512
#define Tt 50
#define NEGC 1000000000.0f
#define CTANH 10.0f

#define OFF_R 0
#define OFF_V 1024
#define OFF_LP 2048
#define OFF_A 2562048
#define OFF_C 2613248
#define OFF_P 2715648

// ws float offsets (all tables; no bulk state)
#define WS_TG 0        // 128 float4 {Mg0, Mg1, vg, cg}
#define WS_TP 512      // 128 float4 {Mp0, Mp1, vp, cp}
#define WS_TQ 1024     // 128 float4 {Pg0, Pg1, cg@Wqp+cp, 0}
#define WS_A0 1536     // 512: We0@Wi
#define WS_A1 2048     // 512: We1@Wi
#define WS_A2 2560     // 512: bemb@Wi + bl
#define WS_A3 3072     // 512: dec_init@Wi + bl   (step 0)
#define WS_CT 3584     // 128 float4 {T0, T1, Tc(+b1), W2}

typedef __attribute__((ext_vector_type(8))) short s16x8;
typedef __attribute__((ext_vector_type(4))) float fx4;

__device__ __forceinline__ float fsig(float x) {
  return __builtin_amdgcn_rcpf(1.0f + __expf(-x));
}

__device__ __forceinline__ float ftanh(float x) {
  float e = __expf(2.0f * x);
  return 1.0f - 2.0f * __builtin_amdgcn_rcpf(e + 1.0f);
}

// fp32 -> bf16 bits, round-to-nearest-even (finite inputs)
__device__ __forceinline__ unsigned short f2bf(float x) {
  unsigned int u = __float_as_uint(x);
  unsigned int r = (u + 0x7fffu + ((u >> 16) & 1u)) >> 16;
  return (unsigned short)r;
}
__device__ __forceinline__ float bf2f(unsigned short b) {
  return __uint_as_float(((unsigned int)b) << 16);
}

__device__ __forceinline__ float dpp_sum_bcast(float x) {
  int v;
  v = __builtin_amdgcn_update_dpp(0, __float_as_int(x), 0x111, 0xf, 0xf, true);
  x += __int_as_float(v);
  v = __builtin_amdgcn_update_dpp(0, __float_as_int(x), 0x112, 0xf, 0xf, true);
  x += __int_as_float(v);
  v = __builtin_amdgcn_update_dpp(0, __float_as_int(x), 0x114, 0xf, 0xf, true);
  x += __int_as_float(v);
  v = __builtin_amdgcn_update_dpp(0, __float_as_int(x), 0x118, 0xf, 0xf, true);
  x += __int_as_float(v);
  v = __builtin_amdgcn_update_dpp(0, __float_as_int(x), 0x142, 0xf, 0xf, true);
  x += __int_as_float(v);
  v = __builtin_amdgcn_update_dpp(0, __float_as_int(x), 0x143, 0xf, 0xf, true);
  x += __int_as_float(v);
  return __int_as_float(__builtin_amdgcn_readlane(__float_as_int(x), 63));
}

// wave64 max via DPP; REQUIRES x >= 0
__device__ __forceinline__ float dpp_max_bcast(float x) {
  int v;
  v = __builtin_amdgcn_update_dpp(0, __float_as_int(x), 0x111, 0xf, 0xf, true);
  x = fmaxf(x, __int_as_float(v));
  v = __builtin_amdgcn_update_dpp(0, __float_as_int(x), 0x112, 0xf, 0xf, true);
  x = fmaxf(x, __int_as_float(v));
  v = __builtin_amdgcn_update_dpp(0, __float_as_int(x), 0x114, 0xf, 0xf, true);
  x = fmaxf(x, __int_as_float(v));
  v = __builtin_amdgcn_update_dpp(0, __float_as_int(x), 0x118, 0xf, 0xf, true);
  x = fmaxf(x, __int_as_float(v));
  v = __builtin_amdgcn_update_dpp(0, __float_as_int(x), 0x142, 0xf, 0xf, true);
  x = fmaxf(x, __int_as_float(v));
  v = __builtin_amdgcn_update_dpp(0, __float_as_int(x), 0x143, 0xf, 0xf, true);
  x = fmaxf(x, __int_as_float(v));
  return __int_as_float(__builtin_amdgcn_readlane(__float_as_int(x), 63));
}

__device__ __forceinline__ float xsum(float x) {
  #pragma unroll
  for (int off = 32; off >= 1; off >>= 1) x += __shfl_xor(x, off, 64);
  return x;
}

// One block, 512 threads: all rank-2 tables + collapsed critic tables.
__global__ __launch_bounds__(512) void k_pre(const float* __restrict__ Wemb,
                                             const float* __restrict__ bemb,
                                             const float* __restrict__ dinit,
                                             const float* __restrict__ Wi,
                                             const float* __restrict__ bl,
                                             const float* __restrict__ Wqp,
                                             const float* __restrict__ Wrg,
                                             const float* __restrict__ Wrp,
                                             const float* __restrict__ vg,
                                             const float* __restrict__ vp,
                                             const float* __restrict__ Wrc,
                                             const float* __restrict__ W1,
                                             const float* __restrict__ b1,
                                             const float* __restrict__ W2,
                                             float* __restrict__ ws) {
  __shared__ float mg_s[2][128], mp_s[2][128], cg_s[128], cp_s[128];
  __shared__ float pg_s[2][128], pc_s[128];
  __shared__ float r0_s[128], r1_s[128], rc_s[128];
  int t = threadIdx.x;
  if (t < 256) {
    int j = t >> 7, hh = t & 127;
    float ag = 0.f, ap = 0.f;
    for (int k = 0; k < 128; ++k) {
      float we = Wemb[j * 128 + k];
      ag = fmaf(we, Wrg[k * 128 + hh], ag);
      ap = fmaf(we, Wrp[k * 128 + hh], ap);
    }
    mg_s[j][hh] = ag; mp_s[j][hh] = ap;
  } else if (t < 384) {
    int hh = t & 127;
    float cgv = 0.f, cpv = 0.f;
    for (int k = 0; k < 128; ++k) {
      float be = bemb[k];
      cgv = fmaf(be, Wrg[k * 128 + hh], cgv);
      cpv = fmaf(be, Wrp[k * 128 + hh], cpv);
    }
    cg_s[hh] = cgv; cp_s[hh] = cpv;
  } else {
    int hh = t & 127;
    float a0 = 0.f, a1 = 0.f, ac = 0.f;
    for (int k = 0; k < 128; ++k) {
      float wr = Wrc[k * 128 + hh];
      a0 = fmaf(Wemb[k], wr, a0);
      a1 = fmaf(Wemb[128 + k], wr, a1);
      ac = fmaf(bemb[k], wr, ac);
    }
    r0_s[hh] = a0; r1_s[hh] = a1; rc_s[hh] = ac;
  }
  __syncthreads();
  if (t < 256) {
    int j = t >> 7, hh = t & 127;
    float pg = 0.f;
    for (int k = 0; k < 128; ++k) pg = fmaf(mg_s[j][k], Wqp[k * 128 + hh], pg);
    pg_s[j][hh] = pg;
  } else if (t < 384) {
    int hh = t & 127;
    float pcv = 0.f;
    for (int k = 0; k < 128; ++k) pcv = fmaf(cg_s[k], Wqp[k * 128 + hh], pcv);
    pc_s[hh] = pcv + cp_s[hh];
  } else {
    int hh = t & 127;
    float t0 = 0.f, t1 = 0.f, tc = 0.f;
    for (int k = 0; k < 128; ++k) {
      float w1 = W1[k * 128 + hh];
      t0 = fmaf(r0_s[k], w1, t0);
      t1 = fmaf(r1_s[k], w1, t1);
      tc = fmaf(rc_s[k], w1, tc);
    }
    float4* w4 = (float4*)ws;
    w4[WS_CT / 4 + hh] = make_float4(t0, t1, tc + b1[hh], W2[hh]);
  }
  __syncthreads();
  if (t < 128) {
    float4* w4 = (float4*)ws;
    w4[WS_TG / 4 + t] = make_float4(mg_s[0][t], mg_s[1][t], vg[t], cg_s[t]);
    w4[WS_TP / 4 + t] = make_float4(mp_s[0][t], mp_s[1][t], vp[t], cp_s[t]);
    w4[WS_TQ / 4 + t] = make_float4(pg_s[0][t], pg_s[1][t], pc_s[t], 0.f);
  }
  {
    int j = t;
    float a0 = 0.f, a1 = 0.f, a2 = 0.f, a3 = 0.f;
    for (int k = 0; k < 128; ++k) {
      float wi = Wi[k * G4 + j];
      a0 = fmaf(Wemb[k], wi, a0);
      a1 = fmaf(Wemb[128 + k], wi, a1);
      a2 = fmaf(bemb[k], wi, a2);
      a3 = fmaf(dinit[k], wi, a3);
    }
    ws[WS_A0 + j] = a0;
    ws[WS_A1 + j] = a1;
    ws[WS_A2 + j] = a2 + bl[j];
    ws[WS_A3 + j] = a3 + bl[j];
  }
}

// Persistent: 256 blocks x 1024 threads (16 waves, 4/SIMD), 4 rows/block.
// NEW vs r0/r4: gates h@Wh moved to the (idle) MFMA pipe via 4-term bf16
// split (hi+lo exact to 2^-18; hihi+hilo+lohi+lolo ~ 1e-7 rel error, below
// accepted rcpf noise). mfma_f32_16x16x32_bf16: M=16 (rows 0-3 live),
// N=512 over 16 waves x 2 tiles, K=128 in 4 steps. k-slot order cancels
// (A and B filled with the same (g,j)->k map). B=Wh hi/lo fragments are
// register-resident (64 VGPRs, replaces wv). A fragments (h hi/lo) built
// once/step by waves 8-11, shared via afrag_s. gpart (64KB) is gone; P2
// reads complete gates. q-broadcast in P4/P5 via v_readlane (bit-identical,
// no LDS round trip). Schedule: 3 block barriers + 2 row-group lsyncs.
__global__ __launch_bounds__(1024, 4) void k_mega(const float* __restrict__ ip,
                                                  const float* __restrict__ Wh,
                                                  const float* __restrict__ Wqg,
                                                  const float* __restrict__ b2,
                                                  const float* __restrict__ ws,
                                                  float* __restrict__ out) {
  __shared__ __align__(16) float gates_s[4][G4];      // 8 KB complete gates
  __shared__ s16x8 afrag_s[4][2][64];                 // 8 KB A hi/lo frags
  __shared__ __align__(16) float qpart[8][4][Hd];     // 16 KB
  __shared__ __align__(16) float up_s[4][4][64];      // 4 KB glimpse partials
  __shared__ __align__(16) float up2_s[4][4][64];     // 4 KB pointer partials
  __shared__ __align__(16) float h_s[4][Hd];
  __shared__ __align__(16) float c_s[4][Hd];
  __shared__ __align__(16) float tg_s[G4];            // {2Mg0,2Mg1,-2vg,2cg}
  __shared__ __align__(16) float tp_s[G4];            // {2Mp0,2Mp1,-2vp,0}
  __shared__ __align__(16) float tq_s[G4];            // {2Pg0,2Pg1,2pc,0}
  __shared__ __align__(16) float ct_s[G4];
  __shared__ __align__(16) float a0_s[G4], a1_s[G4], a2_s[G4], a3_s[G4];
  __shared__ float vsum_s[2][4];                      // sum(v) per 32-h chunk
  __shared__ __align__(16) float ip_s[4][Npt * 2];
  __shared__ float mask_s[4][Npt];
  __shared__ float ch_s[4][Npt * 2];
  __shared__ float sel_s[4][2];
  __shared__ int ctr_s[4];                            // group rendezvous

  int t = threadIdx.x, blk = blockIdx.x;
  int w = t >> 6, lane = t & 63;
  int kh = t >> 7, jt = t & 127;     // 8 k-chunks x 128 cols (P3)
  int k0q = kh * 16;

  // ---- register-resident weights ----
  // B fragments: wave w owns N-cols [32w, 32w+32) as 2 tiles x 4 K-steps,
  // hi/lo bf16. Element (g=lane>>4, j) <-> k = ks*32 + g*8 + j (any
  // consistent map is correct as long as A uses the same one).
  s16x8 Bh[2][4], Bl[2][4];
  {
    int cb = (w << 5) + (lane & 15);
    int g8 = (lane >> 4) << 3;
    #pragma unroll
    for (int tt = 0; tt < 2; ++tt)
      #pragma unroll
      for (int ks = 0; ks < 4; ++ks)
        #pragma unroll
        for (int j = 0; j < 8; ++j) {
          float x = Wh[(size_t)((ks << 5) + g8 + j) * G4 + cb + (tt << 4)];
          unsigned short hb = f2bf(x);
          Bh[tt][ks][j] = (short)hb;
          Bl[tt][ks][j] = (short)f2bf(x - bf2f(hb));
        }
  }
  float wqr[16];                     // Wqg[kh*16 .. +16)[jt]
  #pragma unroll
  for (int j = 0; j < 16; ++j)
    wqr[j] = Wqg[(kh * 16 + j) * Hd + jt];

  // ---- stage tables (x2 pre-scale) + per-block state ----
  const float4* ws4 = (const float4*)ws;
  if (t < 128) {
    float4 g4 = ws4[WS_TG / 4 + t];
    ((float4*)tg_s)[t] = make_float4(2.f * g4.x, 2.f * g4.y, -2.f * g4.z, 2.f * g4.w);
    float4 p4 = ws4[WS_TP / 4 + t];
    ((float4*)tp_s)[t] = make_float4(2.f * p4.x, 2.f * p4.y, -2.f * p4.z, 0.f);
    float4 q4 = ws4[WS_TQ / 4 + t];
    ((float4*)tq_s)[t] = make_float4(2.f * q4.x, 2.f * q4.y, 2.f * q4.z, 0.f);
    ((float4*)ct_s)[t] = ws4[WS_CT / 4 + t];
  } else if (t < 256) {
    int i = t - 128;
    ((float4*)a0_s)[i] = ((const float4*)(ws + WS_A0))[i];
    ((float4*)a1_s)[i] = ((const float4*)(ws + WS_A1))[i];
    ((float4*)a2_s)[i] = ((const float4*)(ws + WS_A2))[i];
    ((float4*)a3_s)[i] = ((const float4*)(ws + WS_A3))[i];
  }
  if (t < 200) {
    ((float2*)ip_s)[t] = ((const float2*)ip)[blk * 200 + t];
    ((float*)mask_s)[t] = 0.f;
  }
  if (t < 512) {
    int r = t >> 7, hh = t & 127;
    h_s[r][hh] = 0.f;
    c_s[r][hh] = 0.f;
  }
  ((float2*)gates_s)[t] = make_float2(0.f, 0.f);   // gates(0) = h0@Wh = 0
  if (t < 8) {          // vsum per 32-h chunk (raw v from ws tables)
    int which = t >> 2, c = t & 3;
    float sv = 0.f;
    for (int hp = 0; hp < 32; ++hp)
      sv += ws[(which ? WS_TP : WS_TG) + (c * 32 + hp) * 4 + 2];
    vsum_s[which][c] = sv;
  }
  if (t < 8) ((float*)sel_s)[t] = 0.f;
  if (t < 4) ctr_s[t] = 0;
  __syncthreads();

  // C/DE/F wave roles: row = w&3, hc = w>>2 in [0,4): 32-h chunk.
  int cr = w & 3, hc = w >> 2;
  float2 pn = make_float2(0.f, 0.f);
  if (lane < Npt) pn = ((float2*)ip_s)[cr * Npt + lane];

  int lt = 0;  // rendezvous target (monotone, +4 per lsync)
  auto lsync = [&]() {
    lt += 4;
    if (lane == 0)
      __hip_atomic_fetch_add(&ctr_s[cr], 1, __ATOMIC_RELEASE,
                             __HIP_MEMORY_SCOPE_WORKGROUP);
    while (__hip_atomic_load(&ctr_s[cr], __ATOMIC_ACQUIRE,
                             __HIP_MEMORY_SCOPE_WORKGROUP) < lt)
      __builtin_amdgcn_s_sleep(1);
  };

  for (int s = 0; s < Tt; ++s) {
    __syncthreads();   // G_a: gates_s(s) + sel/mask(s-1) ready
    // ---- P2: rank-2 x-part + gates + LSTM cell (t<512) ----
    if (t < 512) {
      int r = t >> 7, hh = t & 127;
      float p0 = sel_s[r][0], p1 = sel_s[r][1];
      float g[4];
      #pragma unroll
      for (int gi = 0; gi < 4; ++gi) {
        int j = gi * 128 + hh;
        float x = (s == 0) ? a3_s[j]
                           : fmaf(p0, a0_s[j], fmaf(p1, a1_s[j], a2_s[j]));
        g[gi] = x + gates_s[r][j];
      }
      float c2 = fsig(g[1]) * c_s[r][hh] + fsig(g[0]) * ftanh(g[2]);
      float h2 = fsig(g[3]) * ftanh(c2);
      c_s[r][hh] = c2;
      h_s[r][hh] = h2;
    }
    __syncthreads();   // G_b: h2 ready
    // ---- P3: qpart = h2 @ Wqg (k-split 8-way) + A-frag build (w 8-11) ----
    {
      #pragma unroll
      for (int r = 0; r < 4; ++r) {
        float hv[16];
        #pragma unroll
        for (int q4i = 0; q4i < 4; ++q4i)
          *(float4*)&hv[q4i * 4] = *(const float4*)&h_s[r][k0q + q4i * 4];
        float a = 0.f;
        #pragma unroll
        for (int kk = 0; kk < 16; ++kk) a = fmaf(hv[kk], wqr[kk], a);
        qpart[kh][r][jt] = a;
      }
      if (s + 1 < Tt && w >= 8 && w < 12) {   // build A(h2) hi/lo, K-step w-8
        int ks = w - 8, row = lane & 15, g8 = (lane >> 4) << 3;
        float xv[8];
        if (row < 4) {
          const float* hp8 = &h_s[row][(ks << 5) + g8];
          *(float4*)&xv[0] = *(const float4*)hp8;
          *(float4*)&xv[4] = *(const float4*)(hp8 + 4);
        } else {
          #pragma unroll
          for (int j = 0; j < 8; ++j) xv[j] = 0.f;
        }
        s16x8 hf, lf;
        #pragma unroll
        for (int j = 0; j < 8; ++j) {
          unsigned short hb = f2bf(xv[j]);
          hf[j] = (short)hb;
          lf[j] = (short)f2bf(xv[j] - bf2f(hb));
        }
        afrag_s[ks][0][lane] = hf;
        afrag_s[ks][1][lane] = lf;
      }
    }
    __syncthreads();   // G_c: qpart + afrag ready
    // ---- P4: C glimpse scores; wave=(row,32-h chunk), n per lane ----
    {
      float qs = 0.f;
      if (lane < 32) {                 // q combine (x2 scaled), lanes=h
        int h = hc * 32 + lane;
        qs = ((float4*)tg_s)[h].w
           + 2.f * (qpart[0][cr][h] + qpart[1][cr][h] + qpart[2][cr][h]
                  + qpart[3][cr][h] + qpart[4][cr][h] + qpart[5][cr][h]
                  + qpart[6][cr][h] + qpart[7][cr][h]);
      }
      int qsb = __float_as_int(qs);
      float ac = vsum_s[0][hc];
      #pragma unroll 8
      for (int hp = 0; hp < 32; ++hp) {
        int h = hc * 32 + hp;
        float4 tg4 = ((float4*)tg_s)[h];
        float qv = __int_as_float(__builtin_amdgcn_readlane(qsb, hp));
        float a = fmaf(pn.x, tg4.x, fmaf(pn.y, tg4.y, qv));
        ac = fmaf(tg4.z, __builtin_amdgcn_rcpf(__expf(a) + 1.0f), ac);
      }
      up_s[hc][cr][lane] = ac;
    }
    lsync();           // group: up chunks ready
    // ---- P5: DE glimpse softmax (dup per wave) + pointer scores ----
    {
      float u = up_s[0][cr][lane] + up_s[1][cr][lane]
              + up_s[2][cr][lane] + up_s[3][cr][lane];
      float e = 0.f;
      if (lane < Npt) e = __expf(u - NEGC * mask_s[cr][lane]);
      float ssum = dpp_sum_bcast(e);
      float sx = dpp_sum_bcast(e * pn.x);
      float sy = dpp_sum_bcast(e * pn.y);
      float inv = __builtin_amdgcn_rcpf(ssum);
      float s0 = sx * inv;
      float s1 = sy * inv;
      float qs2 = 0.f;
      if (lane < 32) {
        int h = hc * 32 + lane;
        float4 tq4 = ((float4*)tq_s)[h];
        qs2 = fmaf(s0, tq4.x, fmaf(s1, tq4.y, tq4.z));
      }
      int q2b = __float_as_int(qs2);
      float ac = vsum_s[1][hc];
      #pragma unroll 8
      for (int hp = 0; hp < 32; ++hp) {
        int h = hc * 32 + hp;
        float4 tp4 = ((float4*)tp_s)[h];
        float qv = __int_as_float(__builtin_amdgcn_readlane(q2b, hp));
        float a = fmaf(pn.x, tp4.x, fmaf(pn.y, tp4.y, qv));
        ac = fmaf(tp4.z, __builtin_amdgcn_rcpf(__expf(a) + 1.0f), ac);
      }
      up2_s[hc][cr][lane] = ac;
    }
    lsync();           // group: up2 chunks ready
    // ---- F(s): pointer softmax + argmax + outputs, one wave per row ----
    if (hc == 3) {
      int row = cr, b = blk * 4 + row;
      float u = up2_s[0][row][lane] + up2_s[1][row][lane]
              + up2_s[2][row][lane] + up2_s[3][row][lane];
      float x = 0.f, e = 0.f;
      if (lane < Npt) {
        x = CTANH * ftanh(u) - NEGC * mask_s[row][lane];
        e = __expf(x);
      }
      float ssum = dpp_sum_bcast(e);
      float ls = __logf(ssum);
      float prob = e * __builtin_amdgcn_rcpf(ssum);
      if (lane < Npt) {
        out[OFF_LP + ((size_t)b * Tt + s) * Npt + lane] = x - ls;
        out[OFF_P + ((size_t)b * Tt + s) * Npt + lane] = prob;
      }
      float mx = dpp_max_bcast(prob);
      unsigned long long bal = __ballot((prob == mx) && (lane < Npt));
      int a = __ffsll(bal) - 1;      // first-index tie-break
      float p0a = ip_s[row][2 * a];
      float p1a = ip_s[row][2 * a + 1];
      if (lane == 0) {
        out[OFF_A + (size_t)b * Tt + s] = (float)a;
        out[OFF_C + ((size_t)b * Tt + s) * 2 + 0] = p0a;
        out[OFF_C + ((size_t)b * Tt + s) * 2 + 1] = p1a;
        ((float2*)ch_s)[row * Npt + s] = make_float2(p0a, p1a);
        mask_s[row][a] = 1.0f;
        sel_s[row][0] = p0a;
        sel_s[row][1] = p1a;
      }
    }
    // ---- MFMA: gates(s+1) = h2 @ Wh via 4-term bf16 (all waves) ----
    if (s + 1 < Tt) {
      fx4 d0 = {0.f, 0.f, 0.f, 0.f}, d1 = {0.f, 0.f, 0.f, 0.f};
      #pragma unroll
      for (int ks = 0; ks < 4; ++ks) {
        s16x8 ah = afrag_s[ks][0][lane];
        s16x8 al = afrag_s[ks][1][lane];
        d0 = __builtin_amdgcn_mfma_f32_16x16x32_bf16(ah, Bh[0][ks], d0, 0, 0, 0);
        d0 = __builtin_amdgcn_mfma_f32_16x16x32_bf16(ah, Bl[0][ks], d0, 0, 0, 0);
        d0 = __builtin_amdgcn_mfma_f32_16x16x32_bf16(al, Bh[0][ks], d0, 0, 0, 0);
        d0 = __builtin_amdgcn_mfma_f32_16x16x32_bf16(al, Bl[0][ks], d0, 0, 0, 0);
        d1 = __builtin_amdgcn_mfma_f32_16x16x32_bf16(ah, Bh[1][ks], d1, 0, 0, 0);
        d1 = __builtin_amdgcn_mfma_f32_16x16x32_bf16(ah, Bl[1][ks], d1, 0, 0, 0);
        d1 = __builtin_amdgcn_mfma_f32_16x16x32_bf16(al, Bh[1][ks], d1, 0, 0, 0);
        d1 = __builtin_amdgcn_mfma_f32_16x16x32_bf16(al, Bl[1][ks], d1, 0, 0, 0);
      }
      if (lane < 16) {   // D: col=lane&15, row=(lane>>4)*4+reg -> rows 0-3
        int c0 = (w << 5) + lane;
        #pragma unroll
        for (int rr = 0; rr < 4; ++rr) {
          gates_s[rr][c0] = d0[rr];
          gates_s[rr][c0 + 16] = d1[rr];
        }
      }
    }
  }
  __syncthreads();

  // ---- epilogue: collapsed critic + tour length ----
  if (w < 4) {
    int r = w, b = blk * 4 + r;
    float p0 = sel_s[r][0], p1 = sel_s[r][1];
    float4 ct0 = ((float4*)ct_s)[lane];
    float4 ct1 = ((float4*)ct_s)[64 + lane];
    float t1a = fmaxf(fmaf(p0, ct0.x, fmaf(p1, ct0.y, ct0.z)), 0.f);
    float t1b = fmaxf(fmaf(p0, ct1.x, fmaf(p1, ct1.y, ct1.z)), 0.f);
    float sv = xsum(t1a * ct0.w + t1b * ct1.w);
    if (lane == 0) out[OFF_V + b] = sv + b2[0];
    float rr = 0.f;
    if (lane < Npt) {
      float2 c0 = ((float2*)ch_s)[r * Npt + lane];
      float2 c1 = ((float2*)ch_s)[r * Npt + ((lane == Npt - 1) ? 0 : lane + 1)];
      float dx = c1.x - c0.x, dy = c1.y - c0.y;
      rr = sqrtf(dx * dx + dy * dy + 1e-10f);
    }
    rr = xsum(rr);
    if (lane == 0) out[OFF_R + b] = rr;
  }
}

extern "C" void kernel_launch(void* const* d_in, const int* in_sizes, int n_in,
                              void* d_out, int out_size, void* d_ws, size_t ws_size,
                              hipStream_t stream) {
  (void)in_sizes; (void)n_in; (void)out_size; (void)ws_size;
  const float* ip    = (const float*)d_in[0];
  const float* Wemb  = (const float*)d_in[1];
  const float* bemb  = (const float*)d_in[2];
  const float* dinit = (const float*)d_in[3];
  const float* Wi    = (const float*)d_in[4];
  const float* Wh    = (const float*)d_in[5];
  const float* bl    = (const float*)d_in[6];
  const float* Wqg   = (const float*)d_in[7];
  const float* Wrg   = (const float*)d_in[8];
  const float* vg    = (const float*)d_in[9];
  const float* Wqp   = (const float*)d_in[10];
  const float* Wrp   = (const float*)d_in[11];
  const float* vp    = (const float*)d_in[12];
  // d_in[13..16], d_in[18] dead: critic N=1 softmax == 1 => hy = e_c
  const float* Wrc   = (const float*)d_in[17];
  const float* W1    = (const float*)d_in[19];
  const float* b1    = (const float*)d_in[20];
  const float* W2    = (const float*)d_in[21];
  const float* b2    = (const float*)d_in[22];
  float* out = (float*)d_out;
  float* ws  = (float*)d_ws;

  k_pre<<<1, 512, 0, stream>>>(Wemb, bemb, dinit, Wi, bl, Wqp, Wrg, Wrp,
                               vg, vp, Wrc, W1, b1, W2, ws);
  k_mega<<<256, 1024, 0, stream>>>(ip, Wh, Wqg, b2, ws, out);
}

// Round 6
// 561.171 us; speedup vs baseline: 4.2645x; 1.1114x over previous
//
#include <hip/hip_runtime.h>
#include <math.h>

#define Bsz 1024
#define Npt 50
#define Hd 128
#define G4 512
#define Tt 50
#define NEGC 1000000000.0f
#define CTANH 10.0f
#define L2E 1.44269504088896340736f

#define OFF_R 0
#define OFF_V 1024
#define OFF_LP 2048
#define OFF_A 2562048
#define OFF_C 2613248
#define OFF_P 2715648

// ws float offsets (all tables; no bulk state)
#define WS_TG 0        // 128 float4 {Mg0, Mg1, vg, cg}
#define WS_TP 512      // 128 float4 {Mp0, Mp1, vp, cp}
#define WS_TQ 1024     // 128 float4 {Pg0, Pg1, cg@Wqp+cp, 0}
#define WS_A0 1536     // 512: We0@Wi
#define WS_A1 2048     // 512: We1@Wi
#define WS_A2 2560     // 512: bemb@Wi + bl
#define WS_A3 3072     // 512: dec_init@Wi + bl   (step 0)
#define WS_CT 3584     // 128 float4 {T0, T1, Tc(+b1), W2}

typedef __attribute__((ext_vector_type(8))) short s16x8;
typedef __attribute__((ext_vector_type(4))) float fx4;

// raw v_exp_f32: D = 2^S0 (no hidden log2e multiply)
__device__ __forceinline__ float fexp2(float x) {
  float r;
  asm("v_exp_f32 %0, %1" : "=v"(r) : "v"(x));
  return r;
}

__device__ __forceinline__ float fsig(float x) {
  return __builtin_amdgcn_rcpf(1.0f + __expf(-x));
}

__device__ __forceinline__ float ftanh(float x) {
  float e = __expf(2.0f * x);
  return 1.0f - 2.0f * __builtin_amdgcn_rcpf(e + 1.0f);
}

// fp32 -> bf16 bits, round-to-nearest-even (finite inputs)
__device__ __forceinline__ unsigned short f2bf(float x) {
  unsigned int u = __float_as_uint(x);
  unsigned int r = (u + 0x7fffu + ((u >> 16) & 1u)) >> 16;
  return (unsigned short)r;
}
__device__ __forceinline__ float bf2f(unsigned short b) {
  return __uint_as_float(((unsigned int)b) << 16);
}

__device__ __forceinline__ float dpp_sum_bcast(float x) {
  int v;
  v = __builtin_amdgcn_update_dpp(0, __float_as_int(x), 0x111, 0xf, 0xf, true);
  x += __int_as_float(v);
  v = __builtin_amdgcn_update_dpp(0, __float_as_int(x), 0x112, 0xf, 0xf, true);
  x += __int_as_float(v);
  v = __builtin_amdgcn_update_dpp(0, __float_as_int(x), 0x114, 0xf, 0xf, true);
  x += __int_as_float(v);
  v = __builtin_amdgcn_update_dpp(0, __float_as_int(x), 0x118, 0xf, 0xf, true);
  x += __int_as_float(v);
  v = __builtin_amdgcn_update_dpp(0, __float_as_int(x), 0x142, 0xf, 0xf, true);
  x += __int_as_float(v);
  v = __builtin_amdgcn_update_dpp(0, __float_as_int(x), 0x143, 0xf, 0xf, true);
  x += __int_as_float(v);
  return __int_as_float(__builtin_amdgcn_readlane(__float_as_int(x), 63));
}

// wave64 max via DPP; REQUIRES x >= 0
__device__ __forceinline__ float dpp_max_bcast(float x) {
  int v;
  v = __builtin_amdgcn_update_dpp(0, __float_as_int(x), 0x111, 0xf, 0xf, true);
  x = fmaxf(x, __int_as_float(v));
  v = __builtin_amdgcn_update_dpp(0, __float_as_int(x), 0x112, 0xf, 0xf, true);
  x = fmaxf(x, __int_as_float(v));
  v = __builtin_amdgcn_update_dpp(0, __float_as_int(x), 0x114, 0xf, 0xf, true);
  x = fmaxf(x, __int_as_float(v));
  v = __builtin_amdgcn_update_dpp(0, __float_as_int(x), 0x118, 0xf, 0xf, true);
  x = fmaxf(x, __int_as_float(v));
  v = __builtin_amdgcn_update_dpp(0, __float_as_int(x), 0x142, 0xf, 0xf, true);
  x = fmaxf(x, __int_as_float(v));
  v = __builtin_amdgcn_update_dpp(0, __float_as_int(x), 0x143, 0xf, 0xf, true);
  x = fmaxf(x, __int_as_float(v));
  return __int_as_float(__builtin_amdgcn_readlane(__float_as_int(x), 63));
}

__device__ __forceinline__ float xsum(float x) {
  #pragma unroll
  for (int off = 32; off >= 1; off >>= 1) x += __shfl_xor(x, off, 64);
  return x;
}

// One block, 512 threads: all rank-2 tables + collapsed critic tables.
__global__ __launch_bounds__(512) void k_pre(const float* __restrict__ Wemb,
                                             const float* __restrict__ bemb,
                                             const float* __restrict__ dinit,
                                             const float* __restrict__ Wi,
                                             const float* __restrict__ bl,
                                             const float* __restrict__ Wqp,
                                             const float* __restrict__ Wrg,
                                             const float* __restrict__ Wrp,
                                             const float* __restrict__ vg,
                                             const float* __restrict__ vp,
                                             const float* __restrict__ Wrc,
                                             const float* __restrict__ W1,
                                             const float* __restrict__ b1,
                                             const float* __restrict__ W2,
                                             float* __restrict__ ws) {
  __shared__ float mg_s[2][128], mp_s[2][128], cg_s[128], cp_s[128];
  __shared__ float pg_s[2][128], pc_s[128];
  __shared__ float r0_s[128], r1_s[128], rc_s[128];
  int t = threadIdx.x;
  if (t < 256) {
    int j = t >> 7, hh = t & 127;
    float ag = 0.f, ap = 0.f;
    for (int k = 0; k < 128; ++k) {
      float we = Wemb[j * 128 + k];
      ag = fmaf(we, Wrg[k * 128 + hh], ag);
      ap = fmaf(we, Wrp[k * 128 + hh], ap);
    }
    mg_s[j][hh] = ag; mp_s[j][hh] = ap;
  } else if (t < 384) {
    int hh = t & 127;
    float cgv = 0.f, cpv = 0.f;
    for (int k = 0; k < 128; ++k) {
      float be = bemb[k];
      cgv = fmaf(be, Wrg[k * 128 + hh], cgv);
      cpv = fmaf(be, Wrp[k * 128 + hh], cpv);
    }
    cg_s[hh] = cgv; cp_s[hh] = cpv;
  } else {
    int hh = t & 127;
    float a0 = 0.f, a1 = 0.f, ac = 0.f;
    for (int k = 0; k < 128; ++k) {
      float wr = Wrc[k * 128 + hh];
      a0 = fmaf(Wemb[k], wr, a0);
      a1 = fmaf(Wemb[128 + k], wr, a1);
      ac = fmaf(bemb[k], wr, ac);
    }
    r0_s[hh] = a0; r1_s[hh] = a1; rc_s[hh] = ac;
  }
  __syncthreads();
  if (t < 256) {
    int j = t >> 7, hh = t & 127;
    float pg = 0.f;
    for (int k = 0; k < 128; ++k) pg = fmaf(mg_s[j][k], Wqp[k * 128 + hh], pg);
    pg_s[j][hh] = pg;
  } else if (t < 384) {
    int hh = t & 127;
    float pcv = 0.f;
    for (int k = 0; k < 128; ++k) pcv = fmaf(cg_s[k], Wqp[k * 128 + hh], pcv);
    pc_s[hh] = pcv + cp_s[hh];
  } else {
    int hh = t & 127;
    float t0 = 0.f, t1 = 0.f, tc = 0.f;
    for (int k = 0; k < 128; ++k) {
      float w1 = W1[k * 128 + hh];
      t0 = fmaf(r0_s[k], w1, t0);
      t1 = fmaf(r1_s[k], w1, t1);
      tc = fmaf(rc_s[k], w1, tc);
    }
    float4* w4 = (float4*)ws;
    w4[WS_CT / 4 + hh] = make_float4(t0, t1, tc + b1[hh], W2[hh]);
  }
  __syncthreads();
  if (t < 128) {
    float4* w4 = (float4*)ws;
    w4[WS_TG / 4 + t] = make_float4(mg_s[0][t], mg_s[1][t], vg[t], cg_s[t]);
    w4[WS_TP / 4 + t] = make_float4(mp_s[0][t], mp_s[1][t], vp[t], cp_s[t]);
    w4[WS_TQ / 4 + t] = make_float4(pg_s[0][t], pg_s[1][t], pc_s[t], 0.f);
  }
  {
    int j = t;
    float a0 = 0.f, a1 = 0.f, a2 = 0.f, a3 = 0.f;
    for (int k = 0; k < 128; ++k) {
      float wi = Wi[k * G4 + j];
      a0 = fmaf(Wemb[k], wi, a0);
      a1 = fmaf(Wemb[128 + k], wi, a1);
      a2 = fmaf(bemb[k], wi, a2);
      a3 = fmaf(dinit[k], wi, a3);
    }
    ws[WS_A0 + j] = a0;
    ws[WS_A1 + j] = a1;
    ws[WS_A2 + j] = a2 + bl[j];
    ws[WS_A3 + j] = a3 + bl[j];
  }
}

// Persistent: 256 blocks x 1024 threads (16 waves, 4/SIMD), 4 rows/block.
// r5 base (gates via MFMA 4-term bf16 split) + r6 score-loop diet:
//  - exp2-domain tables (log2e folded at staging) -> raw v_exp_f32, no
//    hidden mul per tuple.
//  - per-step merged table rowt[h] = {2L*M0, 2L*M1, qs, -2v}: loop body is
//    1 ds_read_b128 + 2 fma + exp2 + add + rcp + fma (6 issue slots).
//  - lane repacking: per row 250 active (n, rep) items, 26-h ranges (tables
//    padded to 130 with exact-zero rows); partials in up[rep][n]; full
//    sum(v) added once at combine. 6/1024 lanes idle (was 224).
//  - sync/step: 3 block barriers + 4 row-group lsyncs.
__global__ __launch_bounds__(1024, 4) void k_mega(const float* __restrict__ ip,
                                                  const float* __restrict__ Wh,
                                                  const float* __restrict__ Wqg,
                                                  const float* __restrict__ b2,
                                                  const float* __restrict__ ws,
                                                  float* __restrict__ out) {
  __shared__ __align__(16) float gates_s[4][G4];      // 8 KB complete gates
  __shared__ s16x8 afrag_s[4][2][64];                 // 8 KB A hi/lo frags
  __shared__ __align__(16) float qpart[8][4][Hd];     // 16 KB
  __shared__ __align__(16) float4 rowt_s[4][132];     // 8.25 KB merged tables
  __shared__ __align__(16) float up_s[4][5][64];      // 5 KB glimpse partials
  __shared__ __align__(16) float up2_s[4][5][64];     // 5 KB pointer partials
  __shared__ __align__(16) float h_s[4][Hd];
  __shared__ __align__(16) float c_s[4][Hd];
  __shared__ __align__(16) float tg_s[G4];            // {2L Mg0,2L Mg1,-2vg,2L cg}
  __shared__ __align__(16) float tp_s[G4];            // {2L Mp0,2L Mp1,-2vp,0}
  __shared__ __align__(16) float tq_s[G4];            // {2L Pg0,2L Pg1,2L pc,0}
  __shared__ __align__(16) float ct_s[G4];
  __shared__ __align__(16) float a0_s[G4], a1_s[G4], a2_s[G4], a3_s[G4];
  __shared__ float vt_s[2];                           // full sum(v) g/p
  __shared__ __align__(16) float ip_s[4][Npt * 2];
  __shared__ float mask_s[4][Npt];
  __shared__ float ch_s[4][Npt * 2];
  __shared__ float sel_s[4][2];
  __shared__ int ctr_s[4];                            // group rendezvous

  int t = threadIdx.x, blk = blockIdx.x;
  int w = t >> 6, lane = t & 63;
  int kh = t >> 7, jt = t & 127;     // 8 k-chunks x 128 cols (P3)
  int k0q = kh * 16;

  // ---- register-resident weights ----
  s16x8 Bh[2][4], Bl[2][4];
  {
    int cb = (w << 5) + (lane & 15);
    int g8 = (lane >> 4) << 3;
    #pragma unroll
    for (int tt = 0; tt < 2; ++tt)
      #pragma unroll
      for (int ks = 0; ks < 4; ++ks)
        #pragma unroll
        for (int j = 0; j < 8; ++j) {
          float x = Wh[(size_t)((ks << 5) + g8 + j) * G4 + cb + (tt << 4)];
          unsigned short hb = f2bf(x);
          Bh[tt][ks][j] = (short)hb;
          Bl[tt][ks][j] = (short)f2bf(x - bf2f(hb));
        }
  }
  float wqr[16];                     // Wqg[kh*16 .. +16)[jt]
  #pragma unroll
  for (int j = 0; j < 16; ++j)
    wqr[j] = Wqg[(kh * 16 + j) * Hd + jt];

  // ---- stage tables (2*log2e pre-scale on exp-args) + per-block state ----
  const float4* ws4 = (const float4*)ws;
  if (t < 128) {
    float4 g4 = ws4[WS_TG / 4 + t];
    ((float4*)tg_s)[t] = make_float4(2.f * L2E * g4.x, 2.f * L2E * g4.y,
                                     -2.f * g4.z, 2.f * L2E * g4.w);
    float4 p4 = ws4[WS_TP / 4 + t];
    ((float4*)tp_s)[t] = make_float4(2.f * L2E * p4.x, 2.f * L2E * p4.y,
                                     -2.f * p4.z, 0.f);
    float4 q4 = ws4[WS_TQ / 4 + t];
    ((float4*)tq_s)[t] = make_float4(2.f * L2E * q4.x, 2.f * L2E * q4.y,
                                     2.f * L2E * q4.z, 0.f);
    ((float4*)ct_s)[t] = ws4[WS_CT / 4 + t];
  } else if (t < 256) {
    int i = t - 128;
    ((float4*)a0_s)[i] = ((const float4*)(ws + WS_A0))[i];
    ((float4*)a1_s)[i] = ((const float4*)(ws + WS_A1))[i];
    ((float4*)a2_s)[i] = ((const float4*)(ws + WS_A2))[i];
    ((float4*)a3_s)[i] = ((const float4*)(ws + WS_A3))[i];
  }
  if (t < 200) {
    ((float2*)ip_s)[t] = ((const float2*)ip)[blk * 200 + t];
    ((float*)mask_s)[t] = 0.f;
  }
  if (t < 512) {
    int r = t >> 7, hh = t & 127;
    h_s[r][hh] = 0.f;
    c_s[r][hh] = 0.f;
  }
  ((float2*)gates_s)[t] = make_float2(0.f, 0.f);   // gates(0) = h0@Wh = 0
  if (t < 2) {         // full vsum (raw v from ws tables)
    float sv = 0.f;
    for (int hp = 0; hp < 128; ++hp)
      sv += ws[(t ? WS_TP : WS_TG) + hp * 4 + 2];
    vt_s[t] = sv;
  }
  if (t < 16) {        // zero pad rows 128..131: a=0 -> sig=0.5, z=0 -> +0
    rowt_s[t >> 2][128 + (t & 3)] = make_float4(0.f, 0.f, 0.f, 0.f);
  }
  if (t < 8) ((float*)sel_s)[t] = 0.f;
  if (t < 4) ctr_s[t] = 0;
  __syncthreads();

  // C/DE/F wave roles: row = w&3, hc = w>>2. Score-loop repacking:
  // flat id ell in row-group -> (rep, n2), h-range [26*rep, 26*rep+26).
  int cr = w & 3, hc = w >> 2;
  int ell = hc * 64 + lane;
  int rep = ell / 50;
  bool act = ell < 250;
  int n2 = ell - rep * 50;
  int h0 = rep * 26;
  float2 pw = make_float2(0.f, 0.f);
  if (act) pw = ((float2*)ip_s)[cr * Npt + n2];

  int lt = 0;  // rendezvous target (monotone, +4 per lsync)
  auto lsync = [&]() {
    lt += 4;
    if (lane == 0)
      __hip_atomic_fetch_add(&ctr_s[cr], 1, __ATOMIC_RELEASE,
                             __HIP_MEMORY_SCOPE_WORKGROUP);
    while (__hip_atomic_load(&ctr_s[cr], __ATOMIC_ACQUIRE,
                             __HIP_MEMORY_SCOPE_WORKGROUP) < lt)
      __builtin_amdgcn_s_sleep(1);
  };

  for (int s = 0; s < Tt; ++s) {
    __syncthreads();   // G_a: gates_s(s) + sel/mask(s-1) ready
    // ---- P2: rank-2 x-part + gates + LSTM cell (t<512) ----
    if (t < 512) {
      int r = t >> 7, hh = t & 127;
      float p0 = sel_s[r][0], p1 = sel_s[r][1];
      float g[4];
      #pragma unroll
      for (int gi = 0; gi < 4; ++gi) {
        int j = gi * 128 + hh;
        float x = (s == 0) ? a3_s[j]
                           : fmaf(p0, a0_s[j], fmaf(p1, a1_s[j], a2_s[j]));
        g[gi] = x + gates_s[r][j];
      }
      float c2 = fsig(g[1]) * c_s[r][hh] + fsig(g[0]) * ftanh(g[2]);
      float h2 = fsig(g[3]) * ftanh(c2);
      c_s[r][hh] = c2;
      h_s[r][hh] = h2;
    }
    __syncthreads();   // G_b: h2 ready
    // ---- P3: qpart = h2 @ Wqg (k-split 8-way) + A-frag build (w 8-11) ----
    {
      #pragma unroll
      for (int r = 0; r < 4; ++r) {
        float hv[16];
        #pragma unroll
        for (int q4i = 0; q4i < 4; ++q4i)
          *(float4*)&hv[q4i * 4] = *(const float4*)&h_s[r][k0q + q4i * 4];
        float a = 0.f;
        #pragma unroll
        for (int kk = 0; kk < 16; ++kk) a = fmaf(hv[kk], wqr[kk], a);
        qpart[kh][r][jt] = a;
      }
      if (s + 1 < Tt && w >= 8 && w < 12) {   // build A(h2) hi/lo, K-step w-8
        int ks = w - 8, row = lane & 15, g8 = (lane >> 4) << 3;
        float xv[8];
        if (row < 4) {
          const float* hp8 = &h_s[row][(ks << 5) + g8];
          *(float4*)&xv[0] = *(const float4*)hp8;
          *(float4*)&xv[4] = *(const float4*)(hp8 + 4);
        } else {
          #pragma unroll
          for (int j = 0; j < 8; ++j) xv[j] = 0.f;
        }
        s16x8 hf, lf;
        #pragma unroll
        for (int j = 0; j < 8; ++j) {
          unsigned short hb = f2bf(xv[j]);
          hf[j] = (short)hb;
          lf[j] = (short)f2bf(xv[j] - bf2f(hb));
        }
        afrag_s[ks][0][lane] = hf;
        afrag_s[ks][1][lane] = lf;
      }
    }
    __syncthreads();   // G_c: qpart + afrag ready
    // ---- P4a: merged glimpse table rowt = {x, y, qs, z} (lane<32/wave) ----
    if (lane < 32) {
      int h = hc * 32 + lane;
      float4 tg4 = ((float4*)tg_s)[h];
      float qs = tg4.w + 2.f * L2E *
                 (qpart[0][cr][h] + qpart[1][cr][h] + qpart[2][cr][h]
                + qpart[3][cr][h] + qpart[4][cr][h] + qpart[5][cr][h]
                + qpart[6][cr][h] + qpart[7][cr][h]);
      rowt_s[cr][h] = make_float4(tg4.x, tg4.y, qs, tg4.z);
    }
    lsync();           // rowt(glimpse) ready
    // ---- P4b: glimpse score loop (repacked lanes) ----
    if (act) {
      float ac = 0.f;
      #pragma unroll 13
      for (int i = 0; i < 26; ++i) {
        float4 f4 = rowt_s[cr][h0 + i];
        float a = fmaf(pw.x, f4.x, fmaf(pw.y, f4.y, f4.z));
        ac = fmaf(f4.w, __builtin_amdgcn_rcpf(fexp2(a) + 1.0f), ac);
      }
      up_s[cr][rep][n2] = ac;
    }
    lsync();           // up partials ready
    // ---- P5a: glimpse softmax (dup/wave) + merged pointer table ----
    {
      float u = vt_s[0] + up_s[cr][0][lane] + up_s[cr][1][lane]
              + up_s[cr][2][lane] + up_s[cr][3][lane] + up_s[cr][4][lane];
      float e = 0.f;
      if (lane < Npt) e = __expf(u - NEGC * mask_s[cr][lane]);
      float ssum = dpp_sum_bcast(e);
      float sx = dpp_sum_bcast(e * pw.x * 0.f + e * ((float2*)ip_s)[cr * Npt + (lane < Npt ? lane : 0)].x * (lane < Npt ? 1.f : 0.f));
      // NOTE: sx/sy must use pn indexed by lane (softmax weights), not pw.
      float sy = dpp_sum_bcast(e * ((float2*)ip_s)[cr * Npt + (lane < Npt ? lane : 0)].y * (lane < Npt ? 1.f : 0.f));
      float inv = __builtin_amdgcn_rcpf(ssum);
      float s0 = sx * inv;
      float s1 = sy * inv;
      if (lane < 32) {
        int h = hc * 32 + lane;
        float4 tq4 = ((float4*)tq_s)[h];
        float4 tp4 = ((float4*)tp_s)[h];
        float qs2 = fmaf(s0, tq4.x, fmaf(s1, tq4.y, tq4.z));
        rowt_s[cr][h] = make_float4(tp4.x, tp4.y, qs2, tp4.z);
      }
    }
    lsync();           // rowt(pointer) ready
    // ---- P5b: pointer score loop (repacked lanes) ----
    if (act) {
      float ac = 0.f;
      #pragma unroll 13
      for (int i = 0; i < 26; ++i) {
        float4 f4 = rowt_s[cr][h0 + i];
        float a = fmaf(pw.x, f4.x, fmaf(pw.y, f4.y, f4.z));
        ac = fmaf(f4.w, __builtin_amdgcn_rcpf(fexp2(a) + 1.0f), ac);
      }
      up2_s[cr][rep][n2] = ac;
    }
    lsync();           // up2 partials ready
    // ---- F(s): pointer softmax + argmax + outputs, one wave per row ----
    if (hc == 3) {
      int row = cr, b = blk * 4 + row;
      float u = vt_s[1] + up2_s[row][0][lane] + up2_s[row][1][lane]
              + up2_s[row][2][lane] + up2_s[row][3][lane]
              + up2_s[row][4][lane];
      float x = 0.f, e = 0.f;
      if (lane < Npt) {
        x = CTANH * ftanh(u) - NEGC * mask_s[row][lane];
        e = __expf(x);
      }
      float ssum = dpp_sum_bcast(e);
      float ls = __logf(ssum);
      float prob = e * __builtin_amdgcn_rcpf(ssum);
      if (lane < Npt) {
        out[OFF_LP + ((size_t)b * Tt + s) * Npt + lane] = x - ls;
        out[OFF_P + ((size_t)b * Tt + s) * Npt + lane] = prob;
      }
      float mx = dpp_max_bcast(prob);
      unsigned long long bal = __ballot((prob == mx) && (lane < Npt));
      int a = __ffsll(bal) - 1;      // first-index tie-break
      float p0a = ip_s[row][2 * a];
      float p1a = ip_s[row][2 * a + 1];
      if (lane == 0) {
        out[OFF_A + (size_t)b * Tt + s] = (float)a;
        out[OFF_C + ((size_t)b * Tt + s) * 2 + 0] = p0a;
        out[OFF_C + ((size_t)b * Tt + s) * 2 + 1] = p1a;
        ((float2*)ch_s)[row * Npt + s] = make_float2(p0a, p1a);
        mask_s[row][a] = 1.0f;
        sel_s[row][0] = p0a;
        sel_s[row][1] = p1a;
      }
    }
    // ---- MFMA: gates(s+1) = h2 @ Wh via 4-term bf16 (all waves) ----
    if (s + 1 < Tt) {
      fx4 d0 = {0.f, 0.f, 0.f, 0.f}, d1 = {0.f, 0.f, 0.f, 0.f};
      #pragma unroll
      for (int ks = 0; ks < 4; ++ks) {
        s16x8 ah = afrag_s[ks][0][lane];
        s16x8 al = afrag_s[ks][1][lane];
        d0 = __builtin_amdgcn_mfma_f32_16x16x32_bf16(ah, Bh[0][ks], d0, 0, 0, 0);
        d0 = __builtin_amdgcn_mfma_f32_16x16x32_bf16(ah, Bl[0][ks], d0, 0, 0, 0);
        d0 = __builtin_amdgcn_mfma_f32_16x16x32_bf16(al, Bh[0][ks], d0, 0, 0, 0);
        d0 = __builtin_amdgcn_mfma_f32_16x16x32_bf16(al, Bl[0][ks], d0, 0, 0, 0);
        d1 = __builtin_amdgcn_mfma_f32_16x16x32_bf16(ah, Bh[1][ks], d1, 0, 0, 0);
        d1 = __builtin_amdgcn_mfma_f32_16x16x32_bf16(ah, Bl[1][ks], d1, 0, 0, 0);
        d1 = __builtin_amdgcn_mfma_f32_16x16x32_bf16(al, Bh[1][ks], d1, 0, 0, 0);
        d1 = __builtin_amdgcn_mfma_f32_16x16x32_bf16(al, Bl[1][ks], d1, 0, 0, 0);
      }
      if (lane < 16) {   // D: col=lane&15, row=(lane>>4)*4+reg -> rows 0-3
        int c0 = (w << 5) + lane;
        #pragma unroll
        for (int rr = 0; rr < 4; ++rr) {
          gates_s[rr][c0] = d0[rr];
          gates_s[rr][c0 + 16] = d1[rr];
        }
      }
    }
  }
  __syncthreads();

  // ---- epilogue: collapsed critic + tour length ----
  if (w < 4) {
    int r = w, b = blk * 4 + r;
    float p0 = sel_s[r][0], p1 = sel_s[r][1];
    float4 ct0 = ((float4*)ct_s)[lane];
    float4 ct1 = ((float4*)ct_s)[64 + lane];
    float t1a = fmaxf(fmaf(p0, ct0.x, fmaf(p1, ct0.y, ct0.z)), 0.f);
    float t1b = fmaxf(fmaf(p0, ct1.x, fmaf(p1, ct1.y, ct1.z)), 0.f);
    float sv = xsum(t1a * ct0.w + t1b * ct1.w);
    if (lane == 0) out[OFF_V + b] = sv + b2[0];
    float rr = 0.f;
    if (lane < Npt) {
      float2 c0 = ((float2*)ch_s)[r * Npt + lane];
      float2 c1 = ((float2*)ch_s)[r * Npt + ((lane == Npt - 1) ? 0 : lane + 1)];
      float dx = c1.x - c0.x, dy = c1.y - c0.y;
      rr = sqrtf(dx * dx + dy * dy + 1e-10f);
    }
    rr = xsum(rr);
    if (lane == 0) out[OFF_R + b] = rr;
  }
}

extern "C" void kernel_launch(void* const* d_in, const int* in_sizes, int n_in,
                              void* d_out, int out_size, void* d_ws, size_t ws_size,
                              hipStream_t stream) {
  (void)in_sizes; (void)n_in; (void)out_size; (void)ws_size;
  const float* ip    = (const float*)d_in[0];
  const float* Wemb  = (const float*)d_in[1];
  const float* bemb  = (const float*)d_in[2];
  const float* dinit = (const float*)d_in[3];
  const float* Wi    = (const float*)d_in[4];
  const float* Wh    = (const float*)d_in[5];
  const float* bl    = (const float*)d_in[6];
  const float* Wqg   = (const float*)d_in[7];
  const float* Wrg   = (const float*)d_in[8];
  const float* vg    = (const float*)d_in[9];
  const float* Wqp   = (const float*)d_in[10];
  const float* Wrp   = (const float*)d_in[11];
  const float* vp    = (const float*)d_in[12];
  // d_in[13..16], d_in[18] dead: critic N=1 softmax == 1 => hy = e_c
  const float* Wrc   = (const float*)d_in[17];
  const float* W1    = (const float*)d_in[19];
  const float* b1    = (const float*)d_in[20];
  const float* W2    = (const float*)d_in[21];
  const float* b2    = (const float*)d_in[22];
  float* out = (float*)d_out;
  float* ws  = (float*)d_ws;

  k_pre<<<1, 512, 0, stream>>>(Wemb, bemb, dinit, Wi, bl, Wqp, Wrg, Wrp,
                               vg, vp, Wrc, W1, b1, W2, ws);
  k_mega<<<256, 1024, 0, stream>>>(ip, Wh, Wqg, b2, ws, out);
}